// Round 19
// baseline (860.342 us; speedup 1.0000x reference)
//
#include <hip/hip_runtime.h>
#include <math.h>

// Problem constants (fixed by reference)
#define BB   4
#define SS   4096
#define DD   1024
#define HH   16
#define HDIM 64
#define CC   1024      // MAX_CHUNKS
#define DFF  4096
#define LL   4

static constexpr float F32_EPS = 1.1920928955078125e-07f;  // jnp.finfo(f32).eps

typedef __attribute__((ext_vector_type(8))) __bf16 bf16x8;
typedef __attribute__((ext_vector_type(4))) float  f32x4;

__device__ __forceinline__ uint f2bf(float f) {
    uint u = __float_as_uint(f);
    return (u + 0x7fffu + ((u >> 16) & 1u)) >> 16;   // RNE
}
__device__ __forceinline__ float bf2f(uint u) {
    return __uint_as_float(u << 16);
}

// direct global->LDS DMA, 16 bytes per lane; lds dest must be wave-uniform
__device__ __forceinline__ void gl_lds16(const ushort* g, ushort* l) {
    __builtin_amdgcn_global_load_lds(
        (const __attribute__((address_space(1))) unsigned int*)g,
        (__attribute__((address_space(3))) unsigned int*)l, 16, 0, 0);
}

// ---------------- per-layer mega-cast: all 5 weight mats f32 -> bf16 in one launch --------
__global__ __launch_bounds__(256) void castlayer_kernel(const float* __restrict__ Wq,
                                                        const float* __restrict__ Wk,
                                                        const float* __restrict__ Wv,
                                                        const float* __restrict__ Wo,
                                                        const float* __restrict__ fc,
                                                        const float* __restrict__ proj,
                                                        ushort* __restrict__ out) {
    int i = blockIdx.x * blockDim.x + threadIdx.x;      // 8-elem chunk id, 0..12M/8
    const int U = DD * DD / 8;                          // 131072
    const float* src;
    if (i < 3 * U) {
        src = (i < U ? Wq : (i < 2 * U ? Wk : Wv)) + (size_t)(i < U ? i : (i < 2*U ? i-U : i-2*U)) * 8;
    } else if (i < 4 * U) {
        src = Wo + (size_t)(i - 3 * U) * 8;
    } else if (i < 8 * U) {
        src = fc + (size_t)(i - 4 * U) * 8;
    } else {
        src = proj + (size_t)(i - 8 * U) * 8;
    }
    const float4* p = (const float4*)src;
    float4 a = p[0], b = p[1];
    uint4 o;
    o.x = f2bf(a.x) | (f2bf(a.y) << 16);
    o.y = f2bf(a.z) | (f2bf(a.w) << 16);
    o.z = f2bf(b.x) | (f2bf(b.y) << 16);
    o.w = f2bf(b.z) | (f2bf(b.w) << 16);
    *(uint4*)(out + (size_t)i * 8) = o;
}

// ---------------- RoPE tables ----------------
__global__ void rope_init_kernel(float* __restrict__ cosT, float* __restrict__ sinT) {
    int idx = blockIdx.x * blockDim.x + threadIdx.x;   // over CC*32
    int pos = idx >> 5;
    int i   = idx & 31;
    float inv = powf(10000.0f, -(float)i / 32.0f);
    float f = (float)pos * inv;
    cosT[idx] = cosf(f);
    sinT[idx] = sinf(f);
}

// ---------------- boundary scan -> chunk starts, num_chunks ----------------
__global__ __launch_bounds__(1024) void scan_kernel(const int* __restrict__ boundary,
                                                    int* __restrict__ starts,
                                                    int* __restrict__ nch) {
    __shared__ int tmp[1024];
    int b = blockIdx.x, t = threadIdx.x;
    int base = b * SS + t * 4;
    int v0 = boundary[base + 0], v1 = boundary[base + 1];
    int v2 = boundary[base + 2], v3 = boundary[base + 3];
    int p0 = v0, p1 = p0 + v1, p2 = p1 + v2, p3 = p2 + v3;
    tmp[t] = p3;
    __syncthreads();
    for (int off = 1; off < 1024; off <<= 1) {
        int add = (t >= off) ? tmp[t - off] : 0;
        __syncthreads();
        tmp[t] += add;
        __syncthreads();
    }
    int excl = tmp[t] - p3;
    if (v0) starts[b * (CC + 1) + (excl + p0 - 1)] = t * 4 + 0;
    if (v1) starts[b * (CC + 1) + (excl + p1 - 1)] = t * 4 + 1;
    if (v2) starts[b * (CC + 1) + (excl + p2 - 1)] = t * 4 + 2;
    if (v3) starts[b * (CC + 1) + (excl + p3 - 1)] = t * 4 + 3;
    int total = tmp[1023];
    if (t == 0) nch[b] = total;
    for (int c = t; c <= CC; c += 1024)
        if (c >= total) starts[b * (CC + 1) + c] = SS;
}

// ---------------- chunk means -> h (bf16) and x0 (bf16) ----------------
__global__ __launch_bounds__(256) void latents_kernel(const float* __restrict__ x,
                                                      const int* __restrict__ starts,
                                                      ushort* __restrict__ h,
                                                      ushort* __restrict__ x0) {
    int c = blockIdx.x, b = blockIdx.y, t = threadIdx.x;
    int s0 = starts[b * (CC + 1) + c];
    int s1 = starts[b * (CC + 1) + c + 1];
    float a0 = 0.f, a1 = 0.f, a2 = 0.f, a3 = 0.f;
    for (int r = s0; r < s1; ++r) {
        const float4 xv = *(const float4*)&x[((size_t)(b * SS + r)) * DD + t * 4];
        a0 += xv.x; a1 += xv.y; a2 += xv.z; a3 += xv.w;
    }
    float inv = (s1 > s0) ? 1.0f / (float)(s1 - s0) : 0.0f;
    a0 *= inv; a1 *= inv; a2 *= inv; a3 *= inv;
    size_t off = ((size_t)(b * CC + c)) * DD + t * 4;
    uint2 pk;
    pk.x = f2bf(a0) | (f2bf(a1) << 16);
    pk.y = f2bf(a2) | (f2bf(a3) << 16);
    *(uint2*)&h[off]  = pk;
    *(uint2*)&x0[off] = pk;
}

// ---------------- resid-mix + row RMS norm (layer-0 entry), bf16 h/x0 ----------------
__global__ __launch_bounds__(256) void rmsmix_kernel(const ushort* __restrict__ hin,
                                                     const ushort* __restrict__ x0,
                                                     const float* __restrict__ mix,
                                                     ushort* __restrict__ hout,
                                                     ushort* __restrict__ xnout) {
    int row = blockIdx.x, t = threadIdx.x;
    size_t off = (size_t)row * DD + t * 4;
    uint2 hu = *(const uint2*)&hin[off];
    float4 m0 = *(const float4*)&mix[t * 4];
    float4 m1 = *(const float4*)&mix[DD + t * 4];
    uint2 xv = *(const uint2*)&x0[off];
    float4 hv;
    hv.x = m0.x * bf2f(hu.x & 0xffff) + m1.x * bf2f(xv.x & 0xffff);
    hv.y = m0.y * bf2f(hu.x >> 16)    + m1.y * bf2f(xv.x >> 16);
    hv.z = m0.z * bf2f(hu.y & 0xffff) + m1.z * bf2f(xv.y & 0xffff);
    hv.w = m0.w * bf2f(hu.y >> 16)    + m1.w * bf2f(xv.y >> 16);
    float ss = hv.x * hv.x + hv.y * hv.y + hv.z * hv.z + hv.w * hv.w;
    for (int o = 32; o; o >>= 1) ss += __shfl_xor(ss, o);
    __shared__ float wsum[4];
    int lane = t & 63, wid = t >> 6;
    if (lane == 0) wsum[wid] = ss;
    __syncthreads();
    float tot = wsum[0] + wsum[1] + wsum[2] + wsum[3];
    float r = rsqrtf(tot * (1.0f / DD) + F32_EPS);
    uint2 ph;
    ph.x = f2bf(hv.x) | (f2bf(hv.y) << 16);
    ph.y = f2bf(hv.z) | (f2bf(hv.w) << 16);
    *(uint2*)&hout[off] = ph;
    uint2 pk;
    pk.x = f2bf(hv.x * r) | (f2bf(hv.y * r) << 16);
    pk.y = f2bf(hv.z * r) | (f2bf(hv.w * r) << 16);
    *(uint2*)&xnout[off] = pk;
}

// ---------------- fused: h += scale*(a0+a1); [h = m0*h+m1*x0]; xn = bf16(rms(h)) ---------
// h, a0/a1, x0 all bf16.
template <int HASMIX>
__global__ __launch_bounds__(256) void residrms_kernel(ushort* __restrict__ h,
                                                       const ushort* __restrict__ a0,
                                                       const ushort* __restrict__ a1,
                                                       const float* __restrict__ scale,
                                                       const ushort* __restrict__ x0,
                                                       const float* __restrict__ mix,
                                                       ushort* __restrict__ xnout) {
    int row = blockIdx.x, t = threadIdx.x;
    size_t off = (size_t)row * DD + t * 4;
    uint2 hu = *(const uint2*)&h[off];
    uint2 pa = *(const uint2*)&a0[off];
    uint2 pb = *(const uint2*)&a1[off];
    float4 sv = *(const float4*)&scale[t * 4];
    float4 hv;
    hv.x = bf2f(hu.x & 0xffff) + sv.x * (bf2f(pa.x & 0xffff) + bf2f(pb.x & 0xffff));
    hv.y = bf2f(hu.x >> 16)    + sv.y * (bf2f(pa.x >> 16)    + bf2f(pb.x >> 16));
    hv.z = bf2f(hu.y & 0xffff) + sv.z * (bf2f(pa.y & 0xffff) + bf2f(pb.y & 0xffff));
    hv.w = bf2f(hu.y >> 16)    + sv.w * (bf2f(pa.y >> 16)    + bf2f(pb.y >> 16));
    if (HASMIX) {
        float4 m0 = *(const float4*)&mix[t * 4];
        float4 m1 = *(const float4*)&mix[DD + t * 4];
        uint2 xv = *(const uint2*)&x0[off];
        hv.x = m0.x * hv.x + m1.x * bf2f(xv.x & 0xffff);
        hv.y = m0.y * hv.y + m1.y * bf2f(xv.x >> 16);
        hv.z = m0.z * hv.z + m1.z * bf2f(xv.y & 0xffff);
        hv.w = m0.w * hv.w + m1.w * bf2f(xv.y >> 16);
    }
    float ss = hv.x * hv.x + hv.y * hv.y + hv.z * hv.z + hv.w * hv.w;
    for (int o = 32; o; o >>= 1) ss += __shfl_xor(ss, o);
    __shared__ float wsum[4];
    int lane = t & 63, wid = t >> 6;
    if (lane == 0) wsum[wid] = ss;
    __syncthreads();
    float tot = wsum[0] + wsum[1] + wsum[2] + wsum[3];
    float r = rsqrtf(tot * (1.0f / DD) + F32_EPS);
    uint2 ph;
    ph.x = f2bf(hv.x) | (f2bf(hv.y) << 16);
    ph.y = f2bf(hv.z) | (f2bf(hv.w) << 16);
    *(uint2*)&h[off] = ph;
    uint2 pk;
    pk.x = f2bf(hv.x * r) | (f2bf(hv.y * r) << 16);
    pk.y = f2bf(hv.z * r) | (f2bf(hv.w * r) << 16);
    *(uint2*)&xnout[off] = pk;
}

// ---------------- bf16 MFMA GEMM, 2-phase double-buffered pipeline, 512 threads ----------
// 128x128 tile, BK=32 (LDS 32KB -> 4 blocks/CU, 32 waves/CU), 8 waves 4Mx2N grid.
// XCD remap: 8m x 4n supertiles per XCD chunk (verified r16).
// Staging: 1 gl_lds16/thread/side; source chunk pre-swizzled by (row&3); fragment reads
// fcol = lhi*8 ^ ((l15&3)<<3) -> <=2-way bank conflicts (free).
// EPI 0: bf16 partial store (split-K); EPI 1: relu^2 bf16; EPI 3: fused QKV+qknorm,
// with the v-third written DIRECTLY TRANSPOSED via post-loop LDS transpose (vtrans fused).
template <int EPI>
__global__ __launch_bounds__(512) void gemm_bf16(const ushort* __restrict__ A,
                                                 const ushort* __restrict__ W,
                                                 ushort* __restrict__ C0,
                                                 ushort* __restrict__ C1,
                                                 ushort* __restrict__ C2,
                                                 const float* __restrict__ cosT,
                                                 const float* __restrict__ sinT,
                                                 const float* __restrict__ gain,
                                                 int M, int N, int K, int lda, int ldw,
                                                 size_t partStride) {
    __shared__ __align__(16) ushort Als[2][128 * 32];
    __shared__ __align__(16) ushort Wls[2][128 * 32];
    const int tid  = threadIdx.x;
    const int wid  = tid >> 6, lane = tid & 63;
    const int wr   = wid >> 1, wc   = wid & 1;          // 4x2 wave grid
    const int l15  = lane & 15, lhi = lane >> 4;

    // XCD-aware remap (bijective; all call sites: gy%8==0, gx%4==0, G%8==0)
    const int gx = gridDim.x, gy = gridDim.y, gz = gridDim.z;
    int i = (blockIdx.z * gy + blockIdx.y) * gx + blockIdx.x;
    int G = gx * gy * gz;
    int v = (i & 7) * (G >> 3) + (i >> 3);
    const int SM = 8, SN = 4;
    int r0_ = v % (SM * SN);
    int s_  = v / (SM * SN);
    int mt  = (s_ % (gy / SM)) * SM + (r0_ % SM);
    int s2_ = s_ / (gy / SM);
    int nt  = (s2_ % (gx / SN)) * SN + (r0_ / SM);
    int zt  = s2_ / (gx / SN);
    const int mbase = mt * 128, nbase = nt * 128;

    A  += (size_t)zt * K;
    W  += (size_t)zt * K;
    C0 += (size_t)zt * partStride;

    // staging: thread t covers row tid>>2, 16B chunk (tid&3); source pre-swizzled
    const int srow = tid >> 2;                          // 0..127
    const int gcol = ((tid & 3) ^ (srow & 3)) * 8;      // inverse-swizzled source col
    const ushort* Ag = A + (size_t)(mbase + srow) * lda + gcol;
    const ushort* Wg = W + (size_t)(nbase + srow) * ldw + gcol;
    const int ldsoff = (wid * 16) * 32;                 // wave-uniform LDS base offset

    f32x4 acc[2][4] = {};
    const int swz2 = (l15 & 3) << 3;
    const int fcol = (lhi * 8) ^ swz2;
    const int aoff = (wr * 32 + l15) * 32 + fcol;
    const int woff = (wc * 64 + l15) * 32 + fcol;

    auto STAGE = [&](ushort* Alb, ushort* Wlb, int kk) {
        gl_lds16(Ag + kk, Alb + ldsoff);
        gl_lds16(Wg + kk, Wlb + ldsoff);
    };
    auto COMPUTE = [&](const ushort* Ab, const ushort* Wb) {
        bf16x8 af[2], bfm[4];
#pragma unroll
        for (int m = 0; m < 2; ++m)
            af[m] = *(const bf16x8*)(Ab + aoff + m * 512);
#pragma unroll
        for (int n = 0; n < 4; ++n)
            bfm[n] = *(const bf16x8*)(Wb + woff + n * 512);
#pragma unroll
        for (int m = 0; m < 2; ++m)
#pragma unroll
            for (int n = 0; n < 4; ++n)
                acc[m][n] = __builtin_amdgcn_mfma_f32_16x16x32_bf16(
                    af[m], bfm[n], acc[m][n], 0, 0, 0);
    };

    STAGE(Als[0], Wls[0], 0);
    __syncthreads();
    for (int k0 = 0; k0 < K; k0 += 64) {
        if (k0 + 32 < K) STAGE(Als[1], Wls[1], k0 + 32);
        COMPUTE(Als[0], Wls[0]);
        __syncthreads();
        if (k0 + 64 < K) STAGE(Als[0], Wls[0], k0 + 64);
        COMPUTE(Als[1], Wls[1]);
        __syncthreads();
    }

    const int row0 = mbase + wr * 32 + lhi * 4;

    if (EPI == 3) {
        const int third = nbase >> 10;                  // 0=q, 1=k, 2=v
        const int bandbase = (nbase & 1023) + wc * 64;  // head band start in [0,1024)
        if (third == 2) {
            // --- fused V transpose: acc -> LDS T[d][token^sw] -> vt[(b*16+h)*64+d][token]
            // T uses Als+Wls contiguously? Not contiguous; use dynamic region: reuse both
            // buffers of Als (128*64 ushorts = 16KB) -> need 128*128 = 32KB: use Als & Wls.
            // Als[2] spans 128*64; Wls[2] follows in declaration order but adjacency is
            // not guaranteed -> write halves explicitly.
            ushort* Tlo = Als[0];                       // tokens 0..63   [d][tok^sw]
            ushort* Thi = Wls[0];                       // tokens 64..127 [d][tok^sw]
#pragma unroll
            for (int m = 0; m < 2; ++m)
#pragma unroll
                for (int n = 0; n < 4; ++n) {
                    int co = wc * 64 + n * 16 + l15;    // local d (0..127)
                    int cs = (co & 7) << 3;             // swizzle within 64-token half
#pragma unroll
                    for (int r = 0; r < 4; ++r) {
                        int ro = wr * 32 + m * 16 + lhi * 4 + r;   // local token
                        ushort* Th = (ro & 64) ? Thi : Tlo;
                        Th[co * 64 + ((ro & 63) ^ cs)] = (ushort)f2bf(acc[m][n][r]);
                    }
                }
            __syncthreads();
            const int batch = mbase >> 10;              // one batch per block (M-tile=128)
            const int cbase = mbase & 1023;
            const int hd0   = (nbase - 2048) >> 6;      // first head of this block
            const int co    = tid >> 2;                 // 0..127 (local d)
            const int tch   = (tid & 3) * 8;            // token chunk within 32
            const int csw   = (co & 7) << 3;
            size_t vrow = (size_t)((batch * HH + hd0 + (co >> 6)) * HDIM + (co & 63));
#pragma unroll
            for (int p = 0; p < 4; ++p) {
                int t0 = p * 32 + tch;                  // token 0..127
                const ushort* Th = (t0 & 64) ? Thi : Tlo;
                int4 val = *(const int4*)&Th[co * 64 + ((t0 & 63) ^ csw)];
                *(int4*)&C2[vrow * CC + cbase + t0] = val;
            }
        } else {
            ushort* dst = (third == 0) ? C0 : C1;
            const int hd = bandbase >> 6;
            const float g = (third == 0) ? gain[hd] * 0.125f : 1.0f;
#pragma unroll
            for (int m = 0; m < 2; ++m)
#pragma unroll
                for (int r = 0; r < 4; ++r) {
                    int rr = row0 + m * 16 + r;
                    float v0 = acc[m][0][r], v1 = acc[m][1][r];
                    float v2 = acc[m][2][r], v3 = acc[m][3][r];
                    float ss = v0 * v0 + v1 * v1 + v2 * v2 + v3 * v3;
#pragma unroll
                    for (int off = 1; off < 16; off <<= 1) ss += __shfl_xor(ss, off);
                    float rn = rsqrtf(ss * (1.0f / HDIM) + F32_EPS);
                    v0 *= rn; v1 *= rn; v2 *= rn; v3 *= rn;
                    int c = rr & (CC - 1);
                    float c0 = cosT[c * 32 + l15],      s0 = sinT[c * 32 + l15];
                    float c1 = cosT[c * 32 + 16 + l15], s1 = sinT[c * 32 + 16 + l15];
                    float o0 = (v0 * c0 + v2 * s0) * g;
                    float o1 = (v1 * c1 + v3 * s1) * g;
                    float o2 = (v2 * c0 - v0 * s0) * g;
                    float o3 = (v3 * c1 - v1 * s1) * g;
                    size_t rbase = (size_t)rr * 1024 + bandbase;
                    dst[rbase + l15]      = (ushort)f2bf(o0);
                    dst[rbase + 16 + l15] = (ushort)f2bf(o1);
                    dst[rbase + 32 + l15] = (ushort)f2bf(o2);
                    dst[rbase + 48 + l15] = (ushort)f2bf(o3);
                }
        }
    } else {
        const int col0 = nbase + wc * 64 + l15;
#pragma unroll
        for (int m = 0; m < 2; ++m)
#pragma unroll
            for (int n = 0; n < 4; ++n) {
                int cc = col0 + n * 16;
#pragma unroll
                for (int r = 0; r < 4; ++r) {
                    int rr = row0 + m * 16 + r;
                    float v2 = acc[m][n][r];
                    if (EPI == 1) { v2 = fmaxf(v2, 0.0f); v2 = v2 * v2; }
                    C0[(size_t)rr * N + cc] = (ushort)f2bf(v2);
                }
            }
    }
}

// ---------------- bf16 MFMA causal flash attention: QBLK=128, KVBLK=64, 8 waves (512 thr),
// static-max softmax, double-buffered K/V LDS (ONE barrier per tile), T14 reg prefetch ------
__global__ __launch_bounds__(512) void attn_mfma(const ushort* __restrict__ q,
                                                 const ushort* __restrict__ k,
                                                 const ushort* __restrict__ vt,
                                                 ushort* __restrict__ y,
                                                 const float* __restrict__ gain) {
    __shared__ __align__(16) ushort Qs[128 * 64];    // [qrow][d  ^ sw]
    __shared__ __align__(16) ushort Ks[2][64 * 64];  // [kv]  [d  ^ sw]
    __shared__ __align__(16) ushort VT[2][64 * 64];  // [d]   [kv ^ sw]
    __shared__ __align__(16) ushort Ps[128 * 64];    // [qrow][kv ^ sw] (wave-private rows)
    const int qt = 7 - blockIdx.x;                // longest-first dispatch (qt = 0..7)
    const int head = blockIdx.y, b = blockIdx.z;
    const int tid = threadIdx.x;
    const int wid = tid >> 6, lane = tid & 63;    // 8 waves (512 threads), 16 q-rows each
    const int l15 = lane & 15, lhi = lane >> 4;
    const int wq0 = wid * 16;                     // 0..112
    const int qbase = qt * 128;
    const float mstat = 8.0f * fabsf(gain[head]); // static softmax max bound

    const int srow = tid >> 3;            // 0..63 (512 threads)
    const int scol = (tid & 7) * 8;       // 0..56 step 8

    // stage Q once (128 rows, 2 passes of 64 rows)
#pragma unroll
    for (int s = 0; s < 2; ++s) {
        int r = srow + s * 64;
        int4 t4 = *(const int4*)&q[((size_t)(b * CC + qbase + r)) * DD + head * HDIM + scol];
        *(int4*)&Qs[r * 64 + (scol ^ ((r & 7) << 3))] = t4;
    }

    f32x4 oacc[4] = {};
    float lpart[4] = {0.f, 0.f, 0.f, 0.f};

    const int NT = 2 * qt + 2;            // KV tiles of 64

    int4 kr, vr;
    auto LOADK = [&](int kt_) {
        kr = *(const int4*)&k[((size_t)(b * CC + kt_ * 64 + srow)) * DD + head * HDIM + scol];
        vr = *(const int4*)&vt[((size_t)((b * HH + head) * HDIM + srow)) * CC + kt_ * 64 + scol];
    };
    auto WRITEK = [&](int buf) {
        *(int4*)&Ks[buf][srow * 64 + (scol ^ ((srow & 7) << 3))] = kr;
        *(int4*)&VT[buf][srow * 64 + (scol ^ ((srow & 7) << 3))] = vr;
    };
    auto TILE = [&](int kt, int buf) {
        const ushort* Kb = Ks[buf];
        const ushort* Vb = VT[buf];
        f32x4 sac[4] = {};
        __builtin_amdgcn_s_setprio(1);
#pragma unroll
        for (int ks = 0; ks < 2; ++ks) {
            int dcol = ks * 32 + lhi * 8;
            int arow = wq0 + l15;
            bf16x8 af = *(const bf16x8*)&Qs[arow * 64 + (dcol ^ ((arow & 7) << 3))];
#pragma unroll
            for (int n = 0; n < 4; ++n) {
                int krow = n * 16 + l15;
                bf16x8 bfr = *(const bf16x8*)&Kb[krow * 64 + (dcol ^ ((krow & 7) << 3))];
                sac[n] = __builtin_amdgcn_mfma_f32_16x16x32_bf16(af, bfr, sac[n], 0, 0, 0);
            }
        }
        __builtin_amdgcn_s_setprio(0);

        if (kt >= 2 * qt) {               // diagonal-region tiles (last two)
            const int kb0 = kt * 64;
#pragma unroll
            for (int r = 0; r < 4; ++r) {
                int qrow_g = qbase + wq0 + lhi * 4 + r;
                float p0 = __expf(sac[0][r] - mstat);
                float p1 = __expf(sac[1][r] - mstat);
                float p2 = __expf(sac[2][r] - mstat);
                float p3 = __expf(sac[3][r] - mstat);
                if (kb0 + l15      > qrow_g) p0 = 0.f;
                if (kb0 + 16 + l15 > qrow_g) p1 = 0.f;
                if (kb0 + 32 + l15 > qrow_g) p2 = 0.f;
                if (kb0 + 48 + l15 > qrow_g) p3 = 0.f;
                lpart[r] += (p0 + p1) + (p2 + p3);
                int qrow_l = wq0 + lhi * 4 + r;
                int pb = qrow_l * 64, sw = (qrow_l & 7) << 3;
                Ps[pb + ((l15)      ^ sw)] = (ushort)f2bf(p0);
                Ps[pb + ((16 + l15) ^ sw)] = (ushort)f2bf(p1);
                Ps[pb + ((32 + l15) ^ sw)] = (ushort)f2bf(p2);
                Ps[pb + ((48 + l15) ^ sw)] = (ushort)f2bf(p3);
            }
        } else {
#pragma unroll
            for (int r = 0; r < 4; ++r) {
                float p0 = __expf(sac[0][r] - mstat);
                float p1 = __expf(sac[1][r] - mstat);
                float p2 = __expf(sac[2][r] - mstat);
                float p3 = __expf(sac[3][r] - mstat);
                lpart[r] += (p0 + p1) + (p2 + p3);
                int qrow_l = wq0 + lhi * 4 + r;
                int pb = qrow_l * 64, sw = (qrow_l & 7) << 3;
                Ps[pb + ((l15)      ^ sw)] = (ushort)f2bf(p0);
                Ps[pb + ((16 + l15) ^ sw)] = (ushort)f2bf(p1);
                Ps[pb + ((32 + l15) ^ sw)] = (ushort)f2bf(p2);
                Ps[pb + ((48 + l15) ^ sw)] = (ushort)f2bf(p3);
            }
        }

        __builtin_amdgcn_s_setprio(1);
#pragma unroll
        for (int ks = 0; ks < 2; ++ks) {
            int kcol = ks * 32 + lhi * 8;
            int arow = wq0 + l15;
            bf16x8 pf = *(const bf16x8*)&Ps[arow * 64 + (kcol ^ ((arow & 7) << 3))];
#pragma unroll
            for (int n = 0; n < 4; ++n) {
                int vrow = n * 16 + l15;
                bf16x8 vf = *(const bf16x8*)&Vb[vrow * 64 + (kcol ^ ((vrow & 7) << 3))];
                oacc[n] = __builtin_amdgcn_mfma_f32_16x16x32_bf16(pf, vf, oacc[n], 0, 0, 0);
            }
        }
        __builtin_amdgcn_s_setprio(0);
    };

    // Double-buffered pipeline: ONE barrier per tile.
    LOADK(0);
    WRITEK(0);
    for (int kt = 0; kt < NT; ++kt) {
        if (kt + 1 < NT) LOADK(kt + 1);   // global loads fly under TILE(kt)
        __syncthreads();                  // buf[kt&1] writes visible to all waves
        TILE(kt, kt & 1);
        if (kt + 1 < NT) WRITEK((kt + 1) & 1);
    }

    // single deferred row-sum reduce (16 lanes per row), then divide + store
#pragma unroll
    for (int r = 0; r < 4; ++r) {
        float ls = lpart[r];
#pragma unroll
        for (int off = 1; off < 16; off <<= 1) ls += __shfl_xor(ls, off);
        float inv = 1.0f / ls;
        int qrow_g = qbase + wq0 + lhi * 4 + r;
        size_t base = ((size_t)(b * CC + qrow_g)) * DD + head * HDIM;
#pragma unroll
        for (int n = 0; n < 4; ++n)
            y[base + n * 16 + l15] = (ushort)f2bf(oacc[n][r] * inv);
    }
}

// ---------------- final: out = (h + scale*(a0+a1)) * valid  (h, partials bf16) ------------
__global__ void residmask_kernel(const ushort* __restrict__ h, const ushort* __restrict__ a0,
                                 const ushort* __restrict__ a1,
                                 const float* __restrict__ scale,
                                 const int* __restrict__ nch,
                                 float* __restrict__ out) {
    int idx = blockIdx.x * blockDim.x + threadIdx.x;   // per float4
    size_t off = (size_t)idx * 4;
    int c = (idx >> 8) & (CC - 1);
    int b = idx >> 18;
    uint2 hu = *(const uint2*)&h[off];
    uint2 pa = *(const uint2*)&a0[off];
    uint2 pb = *(const uint2*)&a1[off];
    float4 sv = *(const float4*)&scale[(idx & 255) * 4];
    float4 hv;
    hv.x = bf2f(hu.x & 0xffff) + sv.x * (bf2f(pa.x & 0xffff) + bf2f(pb.x & 0xffff));
    hv.y = bf2f(hu.x >> 16)    + sv.y * (bf2f(pa.x >> 16)    + bf2f(pb.x >> 16));
    hv.z = bf2f(hu.y & 0xffff) + sv.z * (bf2f(pa.y & 0xffff) + bf2f(pb.y & 0xffff));
    hv.w = bf2f(hu.y >> 16)    + sv.w * (bf2f(pa.y >> 16)    + bf2f(pb.y >> 16));
    if (c >= nch[b]) hv = make_float4(0.f, 0.f, 0.f, 0.f);
    *(float4*)&out[off] = hv;
}

extern "C" void kernel_launch(void* const* d_in, const int* in_sizes, int n_in,
                              void* d_out, int out_size, void* d_ws, size_t ws_size,
                              hipStream_t stream) {
    const float* x        = (const float*)d_in[0];
    const int*   boundary = (const int*)d_in[1];
    const float* Wq       = (const float*)d_in[2];
    const float* Wk       = (const float*)d_in[3];
    const float* Wv       = (const float*)d_in[4];
    const float* Wo       = (const float*)d_in[5];
    const float* qg       = (const float*)d_in[6];
    const float* fcw      = (const float*)d_in[7];
    const float* projw    = (const float*)d_in[8];
    const float* ascale   = (const float*)d_in[9];
    const float* mscale   = (const float*)d_in[10];
    const float* rmix     = (const float*)d_in[11];
    float* out = (float*)d_out;

    const size_t NTOK = (size_t)BB * CC * DD;           // 4M elems
    const size_t NHID = (size_t)BB * CC * DFF;          // 16M elems
    const size_t D2   = (size_t)DD * DD;                // 1M elems

    ushort* hb   = (ushort*)d_ws;                       // 4M bf16 residual h
    ushort* x0b  = hb + NTOK;                           // 4M bf16
    ushort* pb0  = x0b + NTOK;                          // 4M bf16 split-K partial 0
    ushort* pb1  = pb0 + NTOK;                          // 4M bf16 split-K partial 1
    ushort* xnb  = pb1 + NTOK;                          // 4M bf16
    ushort* ybf  = xnb + NTOK;                          // 4M bf16
    ushort* hidb = ybf + NTOK;                          // 16M bf16 (q/k during attn)
    ushort* wbuf = hidb + NHID;                         // 16M bf16 weights (12M used)
    ushort* vtb  = wbuf + NHID;                         // 4M bf16 (V transposed, direct)
    float*  cosT = (float*)(vtb + NTOK);
    float*  sinT = cosT + (size_t)CC * 32;
    int*    starts = (int*)(sinT + (size_t)CC * 32);
    int*    nch    = starts + BB * (CC + 1);

    ushort* qbb = hidb;                  // bf16 q (normed+RoPE'd by fused epilogue)
    ushort* kbb = hidb + NTOK;           // bf16 k

    ushort* wqkv = wbuf;                 // [0, 3M)
    ushort* wwo  = wbuf + 3 * D2;        // [3M, 4M)
    ushort* wfc  = wbuf + 4 * D2;        // [4M, 8M)
    ushort* wpj  = wbuf + 8 * D2;        // [8M, 12M)

    const int M = BB * CC;  // 4096 rows
    const int CASTL = (int)(12 * D2 / 8 / 256);         // 6144 blocks

    rope_init_kernel<<<CC * 32 / 256, 256, 0, stream>>>(cosT, sinT);
    scan_kernel<<<BB, 1024, 0, stream>>>(boundary, starts, nch);
    latents_kernel<<<dim3(CC, BB), 256, 0, stream>>>(x, starts, hb, x0b);
    rmsmix_kernel<<<M, 256, 0, stream>>>(hb, x0b, rmix, hb, xnb);   // layer-0 entry

    for (int l = 0; l < LL; ++l) {
        // one mega-cast for all this layer's weights
        castlayer_kernel<<<CASTL, 256, 0, stream>>>(Wq + l * D2, Wk + l * D2, Wv + l * D2,
                                                    Wo + l * D2,
                                                    fcw + (size_t)l * DFF * DD,
                                                    projw + (size_t)l * DD * DFF, wbuf);
        // fused QKV + qknorm epilogue; v written directly transposed into vtb
        gemm_bf16<3><<<dim3(3 * DD / 128, M / 128, 1), 512, 0, stream>>>(
            xnb, wqkv, qbb, kbb, vtb, cosT, sinT, qg + l * HH, M, 3 * DD, DD, DD, DD, 0);
        // MFMA attention -> ybf (QBLK=128, KVBLK=64, dbuf)
        attn_mfma<<<dim3(8, HH, BB), 512, 0, stream>>>(qbb, kbb, vtb, ybf, qg + l * HH);
        // a = y @ Wo^T, split-K=2 -> bf16 partials pb0,pb1; fused resid+rms -> xnb
        gemm_bf16<0><<<dim3(DD / 128, M / 128, 2), 512, 0, stream>>>(
            ybf, wwo, pb0, nullptr, nullptr, nullptr, nullptr, nullptr,
            M, DD, DD / 2, DD, DD, NTOK);
        residrms_kernel<0><<<M, 256, 0, stream>>>(hb, pb0, pb1, ascale + l * DD,
                                                  nullptr, nullptr, xnb);
        // MLP: fc (relu^2, bf16) then proj split-K=2 (bf16 partials)
        gemm_bf16<1><<<dim3(DFF / 128, M / 128, 1), 512, 0, stream>>>(
            xnb, wfc, hidb, nullptr, nullptr, nullptr, nullptr, nullptr,
            M, DFF, DD, DD, DD, 0);
        gemm_bf16<0><<<dim3(DD / 128, M / 128, 2), 512, 0, stream>>>(
            hidb, wpj, pb0, nullptr, nullptr, nullptr, nullptr, nullptr,
            M, DD, DFF / 2, DFF, DFF, NTOK);
        if (l < LL - 1) {
            residrms_kernel<1><<<M, 256, 0, stream>>>(hb, pb0, pb1, mscale + l * DD,
                                                      x0b, rmix + (size_t)(l + 1) * 2 * DD, xnb);
        } else {
            residmask_kernel<<<(int)(NTOK / 4 / 256), 256, 0, stream>>>(
                hb, pb0, pb1, mscale + l * DD, nch, out);
        }
    }
}

// Round 20
// 780.781 us; speedup vs baseline: 1.1019x; 1.1019x over previous
//
#include <hip/hip_runtime.h>
#include <math.h>

// Problem constants (fixed by reference)
#define BB   4
#define SS   4096
#define DD   1024
#define HH   16
#define HDIM 64
#define CC   1024      // MAX_CHUNKS
#define DFF  4096
#define LL   4

static constexpr float F32_EPS = 1.1920928955078125e-07f;  // jnp.finfo(f32).eps

typedef __attribute__((ext_vector_type(8))) __bf16 bf16x8;
typedef __attribute__((ext_vector_type(4))) float  f32x4;

__device__ __forceinline__ uint f2bf(float f) {
    uint u = __float_as_uint(f);
    return (u + 0x7fffu + ((u >> 16) & 1u)) >> 16;   // RNE
}
__device__ __forceinline__ float bf2f(uint u) {
    return __uint_as_float(u << 16);
}

// direct global->LDS DMA, 16 bytes per lane; lds dest must be wave-uniform
__device__ __forceinline__ void gl_lds16(const ushort* g, ushort* l) {
    __builtin_amdgcn_global_load_lds(
        (const __attribute__((address_space(1))) unsigned int*)g,
        (__attribute__((address_space(3))) unsigned int*)l, 16, 0, 0);
}

// ---------------- per-layer mega-cast: all 5 weight mats f32 -> bf16 in one launch --------
__global__ __launch_bounds__(256) void castlayer_kernel(const float* __restrict__ Wq,
                                                        const float* __restrict__ Wk,
                                                        const float* __restrict__ Wv,
                                                        const float* __restrict__ Wo,
                                                        const float* __restrict__ fc,
                                                        const float* __restrict__ proj,
                                                        ushort* __restrict__ out) {
    int i = blockIdx.x * blockDim.x + threadIdx.x;      // 8-elem chunk id, 0..12M/8
    const int U = DD * DD / 8;                          // 131072
    const float* src;
    if (i < 3 * U) {
        src = (i < U ? Wq : (i < 2 * U ? Wk : Wv)) + (size_t)(i < U ? i : (i < 2*U ? i-U : i-2*U)) * 8;
    } else if (i < 4 * U) {
        src = Wo + (size_t)(i - 3 * U) * 8;
    } else if (i < 8 * U) {
        src = fc + (size_t)(i - 4 * U) * 8;
    } else {
        src = proj + (size_t)(i - 8 * U) * 8;
    }
    const float4* p = (const float4*)src;
    float4 a = p[0], b = p[1];
    uint4 o;
    o.x = f2bf(a.x) | (f2bf(a.y) << 16);
    o.y = f2bf(a.z) | (f2bf(a.w) << 16);
    o.z = f2bf(b.x) | (f2bf(b.y) << 16);
    o.w = f2bf(b.z) | (f2bf(b.w) << 16);
    *(uint4*)(out + (size_t)i * 8) = o;
}

// ---------------- RoPE tables ----------------
__global__ void rope_init_kernel(float* __restrict__ cosT, float* __restrict__ sinT) {
    int idx = blockIdx.x * blockDim.x + threadIdx.x;   // over CC*32
    int pos = idx >> 5;
    int i   = idx & 31;
    float inv = powf(10000.0f, -(float)i / 32.0f);
    float f = (float)pos * inv;
    cosT[idx] = cosf(f);
    sinT[idx] = sinf(f);
}

// ---------------- boundary scan -> chunk starts, num_chunks ----------------
__global__ __launch_bounds__(1024) void scan_kernel(const int* __restrict__ boundary,
                                                    int* __restrict__ starts,
                                                    int* __restrict__ nch) {
    __shared__ int tmp[1024];
    int b = blockIdx.x, t = threadIdx.x;
    int base = b * SS + t * 4;
    int v0 = boundary[base + 0], v1 = boundary[base + 1];
    int v2 = boundary[base + 2], v3 = boundary[base + 3];
    int p0 = v0, p1 = p0 + v1, p2 = p1 + v2, p3 = p2 + v3;
    tmp[t] = p3;
    __syncthreads();
    for (int off = 1; off < 1024; off <<= 1) {
        int add = (t >= off) ? tmp[t - off] : 0;
        __syncthreads();
        tmp[t] += add;
        __syncthreads();
    }
    int excl = tmp[t] - p3;
    if (v0) starts[b * (CC + 1) + (excl + p0 - 1)] = t * 4 + 0;
    if (v1) starts[b * (CC + 1) + (excl + p1 - 1)] = t * 4 + 1;
    if (v2) starts[b * (CC + 1) + (excl + p2 - 1)] = t * 4 + 2;
    if (v3) starts[b * (CC + 1) + (excl + p3 - 1)] = t * 4 + 3;
    int total = tmp[1023];
    if (t == 0) nch[b] = total;
    for (int c = t; c <= CC; c += 1024)
        if (c >= total) starts[b * (CC + 1) + c] = SS;
}

// ---------------- chunk means -> h (bf16) and x0 (bf16) ----------------
__global__ __launch_bounds__(256) void latents_kernel(const float* __restrict__ x,
                                                      const int* __restrict__ starts,
                                                      ushort* __restrict__ h,
                                                      ushort* __restrict__ x0) {
    int c = blockIdx.x, b = blockIdx.y, t = threadIdx.x;
    int s0 = starts[b * (CC + 1) + c];
    int s1 = starts[b * (CC + 1) + c + 1];
    float a0 = 0.f, a1 = 0.f, a2 = 0.f, a3 = 0.f;
    for (int r = s0; r < s1; ++r) {
        const float4 xv = *(const float4*)&x[((size_t)(b * SS + r)) * DD + t * 4];
        a0 += xv.x; a1 += xv.y; a2 += xv.z; a3 += xv.w;
    }
    float inv = (s1 > s0) ? 1.0f / (float)(s1 - s0) : 0.0f;
    a0 *= inv; a1 *= inv; a2 *= inv; a3 *= inv;
    size_t off = ((size_t)(b * CC + c)) * DD + t * 4;
    uint2 pk;
    pk.x = f2bf(a0) | (f2bf(a1) << 16);
    pk.y = f2bf(a2) | (f2bf(a3) << 16);
    *(uint2*)&h[off]  = pk;
    *(uint2*)&x0[off] = pk;
}

// ---------------- resid-mix + row RMS norm (layer-0 entry), bf16 h/x0 ----------------
__global__ __launch_bounds__(256) void rmsmix_kernel(const ushort* __restrict__ hin,
                                                     const ushort* __restrict__ x0,
                                                     const float* __restrict__ mix,
                                                     ushort* __restrict__ hout,
                                                     ushort* __restrict__ xnout) {
    int row = blockIdx.x, t = threadIdx.x;
    size_t off = (size_t)row * DD + t * 4;
    uint2 hu = *(const uint2*)&hin[off];
    float4 m0 = *(const float4*)&mix[t * 4];
    float4 m1 = *(const float4*)&mix[DD + t * 4];
    uint2 xv = *(const uint2*)&x0[off];
    float4 hv;
    hv.x = m0.x * bf2f(hu.x & 0xffff) + m1.x * bf2f(xv.x & 0xffff);
    hv.y = m0.y * bf2f(hu.x >> 16)    + m1.y * bf2f(xv.x >> 16);
    hv.z = m0.z * bf2f(hu.y & 0xffff) + m1.z * bf2f(xv.y & 0xffff);
    hv.w = m0.w * bf2f(hu.y >> 16)    + m1.w * bf2f(xv.y >> 16);
    float ss = hv.x * hv.x + hv.y * hv.y + hv.z * hv.z + hv.w * hv.w;
    for (int o = 32; o; o >>= 1) ss += __shfl_xor(ss, o);
    __shared__ float wsum[4];
    int lane = t & 63, wid = t >> 6;
    if (lane == 0) wsum[wid] = ss;
    __syncthreads();
    float tot = wsum[0] + wsum[1] + wsum[2] + wsum[3];
    float r = rsqrtf(tot * (1.0f / DD) + F32_EPS);
    uint2 ph;
    ph.x = f2bf(hv.x) | (f2bf(hv.y) << 16);
    ph.y = f2bf(hv.z) | (f2bf(hv.w) << 16);
    *(uint2*)&hout[off] = ph;
    uint2 pk;
    pk.x = f2bf(hv.x * r) | (f2bf(hv.y * r) << 16);
    pk.y = f2bf(hv.z * r) | (f2bf(hv.w * r) << 16);
    *(uint2*)&xnout[off] = pk;
}

// ---------------- fused: h += scale*(a0+a1); [h = m0*h+m1*x0]; xn = bf16(rms(h)) ---------
// h, a0/a1, x0 all bf16.
template <int HASMIX>
__global__ __launch_bounds__(256) void residrms_kernel(ushort* __restrict__ h,
                                                       const ushort* __restrict__ a0,
                                                       const ushort* __restrict__ a1,
                                                       const float* __restrict__ scale,
                                                       const ushort* __restrict__ x0,
                                                       const float* __restrict__ mix,
                                                       ushort* __restrict__ xnout) {
    int row = blockIdx.x, t = threadIdx.x;
    size_t off = (size_t)row * DD + t * 4;
    uint2 hu = *(const uint2*)&h[off];
    uint2 pa = *(const uint2*)&a0[off];
    uint2 pb = *(const uint2*)&a1[off];
    float4 sv = *(const float4*)&scale[t * 4];
    float4 hv;
    hv.x = bf2f(hu.x & 0xffff) + sv.x * (bf2f(pa.x & 0xffff) + bf2f(pb.x & 0xffff));
    hv.y = bf2f(hu.x >> 16)    + sv.y * (bf2f(pa.x >> 16)    + bf2f(pb.x >> 16));
    hv.z = bf2f(hu.y & 0xffff) + sv.z * (bf2f(pa.y & 0xffff) + bf2f(pb.y & 0xffff));
    hv.w = bf2f(hu.y >> 16)    + sv.w * (bf2f(pa.y >> 16)    + bf2f(pb.y >> 16));
    if (HASMIX) {
        float4 m0 = *(const float4*)&mix[t * 4];
        float4 m1 = *(const float4*)&mix[DD + t * 4];
        uint2 xv = *(const uint2*)&x0[off];
        hv.x = m0.x * hv.x + m1.x * bf2f(xv.x & 0xffff);
        hv.y = m0.y * hv.y + m1.y * bf2f(xv.x >> 16);
        hv.z = m0.z * hv.z + m1.z * bf2f(xv.y & 0xffff);
        hv.w = m0.w * hv.w + m1.w * bf2f(xv.y >> 16);
    }
    float ss = hv.x * hv.x + hv.y * hv.y + hv.z * hv.z + hv.w * hv.w;
    for (int o = 32; o; o >>= 1) ss += __shfl_xor(ss, o);
    __shared__ float wsum[4];
    int lane = t & 63, wid = t >> 6;
    if (lane == 0) wsum[wid] = ss;
    __syncthreads();
    float tot = wsum[0] + wsum[1] + wsum[2] + wsum[3];
    float r = rsqrtf(tot * (1.0f / DD) + F32_EPS);
    uint2 ph;
    ph.x = f2bf(hv.x) | (f2bf(hv.y) << 16);
    ph.y = f2bf(hv.z) | (f2bf(hv.w) << 16);
    *(uint2*)&h[off] = ph;
    uint2 pk;
    pk.x = f2bf(hv.x * r) | (f2bf(hv.y * r) << 16);
    pk.y = f2bf(hv.z * r) | (f2bf(hv.w * r) << 16);
    *(uint2*)&xnout[off] = pk;
}

// ---------------- bf16 MFMA GEMM, 2-phase double-buffered pipeline, 512 threads ----------
// 128x128 tile, BK=64, 8 waves in a 4M x 2N grid (per-wave output 32x64, acc[2][4]).
// XCD remap: 8m x 4n supertiles per XCD chunk (L2-resident A+W slabs, verified r16).
// EPI 0: bf16 partial store (split-K); EPI 1: relu^2 bf16; EPI 3: fused QKV+qknorm,
// with the v-third written DIRECTLY TRANSPOSED via post-loop LDS transpose (vtrans fused).
template <int EPI>
__global__ __launch_bounds__(512) void gemm_bf16(const ushort* __restrict__ A,
                                                 const ushort* __restrict__ W,
                                                 ushort* __restrict__ C0,
                                                 ushort* __restrict__ C1,
                                                 ushort* __restrict__ C2,
                                                 const float* __restrict__ cosT,
                                                 const float* __restrict__ sinT,
                                                 const float* __restrict__ gain,
                                                 int M, int N, int K, int lda, int ldw,
                                                 size_t partStride) {
    __shared__ __align__(16) ushort Als[2][128 * 64];
    __shared__ __align__(16) ushort Wls[2][128 * 64];
    const int tid  = threadIdx.x;
    const int wid  = tid >> 6, lane = tid & 63;
    const int wr   = wid >> 1, wc   = wid & 1;          // 4x2 wave grid
    const int l15  = lane & 15, lhi = lane >> 4;

    // XCD-aware remap (bijective; all call sites: gy%8==0, gx%4==0, G%8==0)
    const int gx = gridDim.x, gy = gridDim.y, gz = gridDim.z;
    int i = (blockIdx.z * gy + blockIdx.y) * gx + blockIdx.x;
    int G = gx * gy * gz;
    int v = (i & 7) * (G >> 3) + (i >> 3);
    const int SM = 8, SN = 4;
    int r0_ = v % (SM * SN);
    int s_  = v / (SM * SN);
    int mt  = (s_ % (gy / SM)) * SM + (r0_ % SM);
    int s2_ = s_ / (gy / SM);
    int nt  = (s2_ % (gx / SN)) * SN + (r0_ / SM);
    int zt  = s2_ / (gx / SN);
    const int mbase = mt * 128, nbase = nt * 128;

    A  += (size_t)zt * K;
    W  += (size_t)zt * K;
    C0 += (size_t)zt * partStride;

    const int srow8  = lane >> 3;                       // 0..7
    const int gchunk = ((lane & 7) ^ srow8) * 8;        // inverse-swizzled source chunk
    const ushort* Ag = A + (size_t)(mbase + wid * 16 + srow8) * lda + gchunk;
    const ushort* Wg = W + (size_t)(nbase + wid * 16 + srow8) * ldw + gchunk;
    const int ldsoff = (wid * 16) * 64;                 // wave-uniform LDS base offset

    f32x4 acc[2][4] = {};
    const int swz  = (l15 & 7) << 3;
    const int aoff = (wr * 32 + l15) * 64;
    const int woff = (wc * 64 + l15) * 64;

    auto STAGE = [&](ushort* Alb, ushort* Wlb, int kk) {
#pragma unroll
        for (int s = 0; s < 2; ++s) {
            gl_lds16(Ag + kk + (size_t)s * 8 * lda, Alb + ldsoff + s * 8 * 64);
            gl_lds16(Wg + kk + (size_t)s * 8 * ldw, Wlb + ldsoff + s * 8 * 64);
        }
    };
    auto COMPUTE = [&](const ushort* Ab, const ushort* Wb) {
#pragma unroll
        for (int ks = 0; ks < 2; ++ks) {
            const int fcol = (ks * 32 + lhi * 8) ^ swz;
            bf16x8 af[2], bfm[4];
#pragma unroll
            for (int m = 0; m < 2; ++m)
                af[m] = *(const bf16x8*)(Ab + aoff + m * 1024 + fcol);
#pragma unroll
            for (int n = 0; n < 4; ++n)
                bfm[n] = *(const bf16x8*)(Wb + woff + n * 1024 + fcol);
#pragma unroll
            for (int m = 0; m < 2; ++m)
#pragma unroll
                for (int n = 0; n < 4; ++n)
                    acc[m][n] = __builtin_amdgcn_mfma_f32_16x16x32_bf16(
                        af[m], bfm[n], acc[m][n], 0, 0, 0);
        }
    };

    STAGE(Als[0], Wls[0], 0);
    __syncthreads();
    for (int k0 = 0; k0 < K; k0 += 128) {
        if (k0 + 64 < K) STAGE(Als[1], Wls[1], k0 + 64);
        COMPUTE(Als[0], Wls[0]);
        __syncthreads();
        if (k0 + 128 < K) STAGE(Als[0], Wls[0], k0 + 128);
        COMPUTE(Als[1], Wls[1]);
        __syncthreads();
    }

    const int row0 = mbase + wr * 32 + lhi * 4;

    if (EPI == 3) {
        const int third = nbase >> 10;                  // 0=q, 1=k, 2=v
        const int bandbase = (nbase & 1023) + wc * 64;  // head band start in [0,1024)
        if (third == 2) {
            // --- fused V transpose: acc -> LDS T[d][token^sw] -> vt[(b*16+h)*64+d][token]
            // swizzle (co&15)<<3 spreads banks by (co&7)*4 -> <=2-way conflicts
            ushort* T = Als[0];                         // 2x(128*64) = 128*128 ushorts
#pragma unroll
            for (int m = 0; m < 2; ++m)
#pragma unroll
                for (int n = 0; n < 4; ++n) {
                    int co = wc * 64 + n * 16 + l15;    // local d   (0..127)
                    int cs = (co & 15) << 3;
#pragma unroll
                    for (int r = 0; r < 4; ++r) {
                        int ro = wr * 32 + m * 16 + lhi * 4 + r;   // local token
                        T[co * 128 + (ro ^ cs)] = (ushort)f2bf(acc[m][n][r]);
                    }
                }
            __syncthreads();
            const int batch = mbase >> 10;              // one batch per block (M-tile=128)
            const int cbase = mbase & 1023;
            const int hd0   = (nbase - 2048) >> 6;      // first head of this block
            const int co    = tid >> 2;                 // 0..127 (local d)
            const int tch   = (tid & 3) * 8;            // token chunk within 32
            const int csw   = (co & 15) << 3;
            size_t vrow = (size_t)((batch * HH + hd0 + (co >> 6)) * HDIM + (co & 63));
#pragma unroll
            for (int p = 0; p < 4; ++p) {
                int t0 = p * 32 + tch;
                int4 val = *(const int4*)&T[co * 128 + (t0 ^ csw)];
                *(int4*)&C2[vrow * CC + cbase + t0] = val;
            }
        } else {
            ushort* dst = (third == 0) ? C0 : C1;
            const int hd = bandbase >> 6;
            const float g = (third == 0) ? gain[hd] * 0.125f : 1.0f;
#pragma unroll
            for (int m = 0; m < 2; ++m)
#pragma unroll
                for (int r = 0; r < 4; ++r) {
                    int rr = row0 + m * 16 + r;
                    float v0 = acc[m][0][r], v1 = acc[m][1][r];
                    float v2 = acc[m][2][r], v3 = acc[m][3][r];
                    float ss = v0 * v0 + v1 * v1 + v2 * v2 + v3 * v3;
#pragma unroll
                    for (int off = 1; off < 16; off <<= 1) ss += __shfl_xor(ss, off);
                    float rn = rsqrtf(ss * (1.0f / HDIM) + F32_EPS);
                    v0 *= rn; v1 *= rn; v2 *= rn; v3 *= rn;
                    int c = rr & (CC - 1);
                    float c0 = cosT[c * 32 + l15],      s0 = sinT[c * 32 + l15];
                    float c1 = cosT[c * 32 + 16 + l15], s1 = sinT[c * 32 + 16 + l15];
                    float o0 = (v0 * c0 + v2 * s0) * g;
                    float o1 = (v1 * c1 + v3 * s1) * g;
                    float o2 = (v2 * c0 - v0 * s0) * g;
                    float o3 = (v3 * c1 - v1 * s1) * g;
                    size_t rbase = (size_t)rr * 1024 + bandbase;
                    dst[rbase + l15]      = (ushort)f2bf(o0);
                    dst[rbase + 16 + l15] = (ushort)f2bf(o1);
                    dst[rbase + 32 + l15] = (ushort)f2bf(o2);
                    dst[rbase + 48 + l15] = (ushort)f2bf(o3);
                }
        }
    } else {
        const int col0 = nbase + wc * 64 + l15;
#pragma unroll
        for (int m = 0; m < 2; ++m)
#pragma unroll
            for (int n = 0; n < 4; ++n) {
                int cc = col0 + n * 16;
#pragma unroll
                for (int r = 0; r < 4; ++r) {
                    int rr = row0 + m * 16 + r;
                    float v2 = acc[m][n][r];
                    if (EPI == 1) { v2 = fmaxf(v2, 0.0f); v2 = v2 * v2; }
                    C0[(size_t)rr * N + cc] = (ushort)f2bf(v2);
                }
            }
    }
}

// ---------------- bf16 MFMA causal flash attention: QBLK=128, KVBLK=64, 8 waves (512 thr),
// static-max softmax, double-buffered K/V LDS (ONE barrier per tile), T14 reg prefetch ------
__global__ __launch_bounds__(512) void attn_mfma(const ushort* __restrict__ q,
                                                 const ushort* __restrict__ k,
                                                 const ushort* __restrict__ vt,
                                                 ushort* __restrict__ y,
                                                 const float* __restrict__ gain) {
    __shared__ __align__(16) ushort Qs[128 * 64];    // [qrow][d  ^ sw]
    __shared__ __align__(16) ushort Ks[2][64 * 64];  // [kv]  [d  ^ sw]
    __shared__ __align__(16) ushort VT[2][64 * 64];  // [d]   [kv ^ sw]
    __shared__ __align__(16) ushort Ps[128 * 64];    // [qrow][kv ^ sw] (wave-private rows)
    const int qt = 7 - blockIdx.x;                // longest-first dispatch (qt = 0..7)
    const int head = blockIdx.y, b = blockIdx.z;
    const int tid = threadIdx.x;
    const int wid = tid >> 6, lane = tid & 63;    // 8 waves (512 threads), 16 q-rows each
    const int l15 = lane & 15, lhi = lane >> 4;
    const int wq0 = wid * 16;                     // 0..112
    const int qbase = qt * 128;
    const float mstat = 8.0f * fabsf(gain[head]); // static softmax max bound

    const int srow = tid >> 3;            // 0..63 (512 threads)
    const int scol = (tid & 7) * 8;       // 0..56 step 8

    // stage Q once (128 rows, 2 passes of 64 rows)
#pragma unroll
    for (int s = 0; s < 2; ++s) {
        int r = srow + s * 64;
        int4 t4 = *(const int4*)&q[((size_t)(b * CC + qbase + r)) * DD + head * HDIM + scol];
        *(int4*)&Qs[r * 64 + (scol ^ ((r & 7) << 3))] = t4;
    }

    f32x4 oacc[4] = {};
    float lpart[4] = {0.f, 0.f, 0.f, 0.f};

    const int NT = 2 * qt + 2;            // KV tiles of 64

    int4 kr, vr;
    auto LOADK = [&](int kt_) {
        kr = *(const int4*)&k[((size_t)(b * CC + kt_ * 64 + srow)) * DD + head * HDIM + scol];
        vr = *(const int4*)&vt[((size_t)((b * HH + head) * HDIM + srow)) * CC + kt_ * 64 + scol];
    };
    auto WRITEK = [&](int buf) {
        *(int4*)&Ks[buf][srow * 64 + (scol ^ ((srow & 7) << 3))] = kr;
        *(int4*)&VT[buf][srow * 64 + (scol ^ ((srow & 7) << 3))] = vr;
    };
    auto TILE = [&](int kt, int buf) {
        const ushort* Kb = Ks[buf];
        const ushort* Vb = VT[buf];
        f32x4 sac[4] = {};
        __builtin_amdgcn_s_setprio(1);
#pragma unroll
        for (int ks = 0; ks < 2; ++ks) {
            int dcol = ks * 32 + lhi * 8;
            int arow = wq0 + l15;
            bf16x8 af = *(const bf16x8*)&Qs[arow * 64 + (dcol ^ ((arow & 7) << 3))];
#pragma unroll
            for (int n = 0; n < 4; ++n) {
                int krow = n * 16 + l15;
                bf16x8 bfr = *(const bf16x8*)&Kb[krow * 64 + (dcol ^ ((krow & 7) << 3))];
                sac[n] = __builtin_amdgcn_mfma_f32_16x16x32_bf16(af, bfr, sac[n], 0, 0, 0);
            }
        }
        __builtin_amdgcn_s_setprio(0);

        if (kt >= 2 * qt) {               // diagonal-region tiles (last two)
            const int kb0 = kt * 64;
#pragma unroll
            for (int r = 0; r < 4; ++r) {
                int qrow_g = qbase + wq0 + lhi * 4 + r;
                float p0 = __expf(sac[0][r] - mstat);
                float p1 = __expf(sac[1][r] - mstat);
                float p2 = __expf(sac[2][r] - mstat);
                float p3 = __expf(sac[3][r] - mstat);
                if (kb0 + l15      > qrow_g) p0 = 0.f;
                if (kb0 + 16 + l15 > qrow_g) p1 = 0.f;
                if (kb0 + 32 + l15 > qrow_g) p2 = 0.f;
                if (kb0 + 48 + l15 > qrow_g) p3 = 0.f;
                lpart[r] += (p0 + p1) + (p2 + p3);
                int qrow_l = wq0 + lhi * 4 + r;
                int pb = qrow_l * 64, sw = (qrow_l & 7) << 3;
                Ps[pb + ((l15)      ^ sw)] = (ushort)f2bf(p0);
                Ps[pb + ((16 + l15) ^ sw)] = (ushort)f2bf(p1);
                Ps[pb + ((32 + l15) ^ sw)] = (ushort)f2bf(p2);
                Ps[pb + ((48 + l15) ^ sw)] = (ushort)f2bf(p3);
            }
        } else {
#pragma unroll
            for (int r = 0; r < 4; ++r) {
                float p0 = __expf(sac[0][r] - mstat);
                float p1 = __expf(sac[1][r] - mstat);
                float p2 = __expf(sac[2][r] - mstat);
                float p3 = __expf(sac[3][r] - mstat);
                lpart[r] += (p0 + p1) + (p2 + p3);
                int qrow_l = wq0 + lhi * 4 + r;
                int pb = qrow_l * 64, sw = (qrow_l & 7) << 3;
                Ps[pb + ((l15)      ^ sw)] = (ushort)f2bf(p0);
                Ps[pb + ((16 + l15) ^ sw)] = (ushort)f2bf(p1);
                Ps[pb + ((32 + l15) ^ sw)] = (ushort)f2bf(p2);
                Ps[pb + ((48 + l15) ^ sw)] = (ushort)f2bf(p3);
            }
        }

        __builtin_amdgcn_s_setprio(1);
#pragma unroll
        for (int ks = 0; ks < 2; ++ks) {
            int kcol = ks * 32 + lhi * 8;
            int arow = wq0 + l15;
            bf16x8 pf = *(const bf16x8*)&Ps[arow * 64 + (kcol ^ ((arow & 7) << 3))];
#pragma unroll
            for (int n = 0; n < 4; ++n) {
                int vrow = n * 16 + l15;
                bf16x8 vf = *(const bf16x8*)&Vb[vrow * 64 + (kcol ^ ((vrow & 7) << 3))];
                oacc[n] = __builtin_amdgcn_mfma_f32_16x16x32_bf16(pf, vf, oacc[n], 0, 0, 0);
            }
        }
        __builtin_amdgcn_s_setprio(0);
    };

    // Double-buffered pipeline: ONE barrier per tile.
    LOADK(0);
    WRITEK(0);
    for (int kt = 0; kt < NT; ++kt) {
        if (kt + 1 < NT) LOADK(kt + 1);   // global loads fly under TILE(kt)
        __syncthreads();                  // buf[kt&1] writes visible to all waves
        TILE(kt, kt & 1);
        if (kt + 1 < NT) WRITEK((kt + 1) & 1);
    }

    // single deferred row-sum reduce (16 lanes per row), then divide + store
#pragma unroll
    for (int r = 0; r < 4; ++r) {
        float ls = lpart[r];
#pragma unroll
        for (int off = 1; off < 16; off <<= 1) ls += __shfl_xor(ls, off);
        float inv = 1.0f / ls;
        int qrow_g = qbase + wq0 + lhi * 4 + r;
        size_t base = ((size_t)(b * CC + qrow_g)) * DD + head * HDIM;
#pragma unroll
        for (int n = 0; n < 4; ++n)
            y[base + n * 16 + l15] = (ushort)f2bf(oacc[n][r] * inv);
    }
}

// ---------------- final: out = (h + scale*(a0+a1)) * valid  (h, partials bf16) ------------
__global__ void residmask_kernel(const ushort* __restrict__ h, const ushort* __restrict__ a0,
                                 const ushort* __restrict__ a1,
                                 const float* __restrict__ scale,
                                 const int* __restrict__ nch,
                                 float* __restrict__ out) {
    int idx = blockIdx.x * blockDim.x + threadIdx.x;   // per float4
    size_t off = (size_t)idx * 4;
    int c = (idx >> 8) & (CC - 1);
    int b = idx >> 18;
    uint2 hu = *(const uint2*)&h[off];
    uint2 pa = *(const uint2*)&a0[off];
    uint2 pb = *(const uint2*)&a1[off];
    float4 sv = *(const float4*)&scale[(idx & 255) * 4];
    float4 hv;
    hv.x = bf2f(hu.x & 0xffff) + sv.x * (bf2f(pa.x & 0xffff) + bf2f(pb.x & 0xffff));
    hv.y = bf2f(hu.x >> 16)    + sv.y * (bf2f(pa.x >> 16)    + bf2f(pb.x >> 16));
    hv.z = bf2f(hu.y & 0xffff) + sv.z * (bf2f(pa.y & 0xffff) + bf2f(pb.y & 0xffff));
    hv.w = bf2f(hu.y >> 16)    + sv.w * (bf2f(pa.y >> 16)    + bf2f(pb.y >> 16));
    if (c >= nch[b]) hv = make_float4(0.f, 0.f, 0.f, 0.f);
    *(float4*)&out[off] = hv;
}

extern "C" void kernel_launch(void* const* d_in, const int* in_sizes, int n_in,
                              void* d_out, int out_size, void* d_ws, size_t ws_size,
                              hipStream_t stream) {
    const float* x        = (const float*)d_in[0];
    const int*   boundary = (const int*)d_in[1];
    const float* Wq       = (const float*)d_in[2];
    const float* Wk       = (const float*)d_in[3];
    const float* Wv       = (const float*)d_in[4];
    const float* Wo       = (const float*)d_in[5];
    const float* qg       = (const float*)d_in[6];
    const float* fcw      = (const float*)d_in[7];
    const float* projw    = (const float*)d_in[8];
    const float* ascale   = (const float*)d_in[9];
    const float* mscale   = (const float*)d_in[10];
    const float* rmix     = (const float*)d_in[11];
    float* out = (float*)d_out;

    const size_t NTOK = (size_t)BB * CC * DD;           // 4M elems
    const size_t NHID = (size_t)BB * CC * DFF;          // 16M elems
    const size_t D2   = (size_t)DD * DD;                // 1M elems

    ushort* hb   = (ushort*)d_ws;                       // 4M bf16 residual h
    ushort* x0b  = hb + NTOK;                           // 4M bf16
    ushort* pb0  = x0b + NTOK;                          // 4M bf16 split-K partial 0
    ushort* pb1  = pb0 + NTOK;                          // 4M bf16 split-K partial 1
    ushort* xnb  = pb1 + NTOK;                          // 4M bf16
    ushort* ybf  = xnb + NTOK;                          // 4M bf16
    ushort* hidb = ybf + NTOK;                          // 16M bf16 (q/k during attn)
    ushort* wbuf = hidb + NHID;                         // 16M bf16 weights (12M used)
    ushort* vtb  = wbuf + NHID;                         // 4M bf16 (V transposed, direct)
    float*  cosT = (float*)(vtb + NTOK);
    float*  sinT = cosT + (size_t)CC * 32;
    int*    starts = (int*)(sinT + (size_t)CC * 32);
    int*    nch    = starts + BB * (CC + 1);

    ushort* qbb = hidb;                  // bf16 q (normed+RoPE'd by fused epilogue)
    ushort* kbb = hidb + NTOK;           // bf16 k

    ushort* wqkv = wbuf;                 // [0, 3M)
    ushort* wwo  = wbuf + 3 * D2;        // [3M, 4M)
    ushort* wfc  = wbuf + 4 * D2;        // [4M, 8M)
    ushort* wpj  = wbuf + 8 * D2;        // [8M, 12M)

    const int M = BB * CC;  // 4096 rows
    const int CASTL = (int)(12 * D2 / 8 / 256);         // 6144 blocks

    rope_init_kernel<<<CC * 32 / 256, 256, 0, stream>>>(cosT, sinT);
    scan_kernel<<<BB, 1024, 0, stream>>>(boundary, starts, nch);
    latents_kernel<<<dim3(CC, BB), 256, 0, stream>>>(x, starts, hb, x0b);
    rmsmix_kernel<<<M, 256, 0, stream>>>(hb, x0b, rmix, hb, xnb);   // layer-0 entry

    for (int l = 0; l < LL; ++l) {
        // one mega-cast for all this layer's weights
        castlayer_kernel<<<CASTL, 256, 0, stream>>>(Wq + l * D2, Wk + l * D2, Wv + l * D2,
                                                    Wo + l * D2,
                                                    fcw + (size_t)l * DFF * DD,
                                                    projw + (size_t)l * DD * DFF, wbuf);
        // fused QKV + qknorm epilogue; v written directly transposed into vtb
        gemm_bf16<3><<<dim3(3 * DD / 128, M / 128, 1), 512, 0, stream>>>(
            xnb, wqkv, qbb, kbb, vtb, cosT, sinT, qg + l * HH, M, 3 * DD, DD, DD, DD, 0);
        // MFMA attention -> ybf (QBLK=128, KVBLK=64, dbuf)
        attn_mfma<<<dim3(8, HH, BB), 512, 0, stream>>>(qbb, kbb, vtb, ybf, qg + l * HH);
        // a = y @ Wo^T, split-K=2 -> bf16 partials pb0,pb1; fused resid+rms -> xnb
        gemm_bf16<0><<<dim3(DD / 128, M / 128, 2), 512, 0, stream>>>(
            ybf, wwo, pb0, nullptr, nullptr, nullptr, nullptr, nullptr,
            M, DD, DD / 2, DD, DD, NTOK);
        residrms_kernel<0><<<M, 256, 0, stream>>>(hb, pb0, pb1, ascale + l * DD,
                                                  nullptr, nullptr, xnb);
        // MLP: fc (relu^2, bf16) then proj split-K=2 (bf16 partials)
        gemm_bf16<1><<<dim3(DFF / 128, M / 128, 1), 512, 0, stream>>>(
            xnb, wfc, hidb, nullptr, nullptr, nullptr, nullptr, nullptr,
            M, DFF, DD, DD, DD, 0);
        gemm_bf16<0><<<dim3(DD / 128, M / 128, 2), 512, 0, stream>>>(
            hidb, wpj, pb0, nullptr, nullptr, nullptr, nullptr, nullptr,
            M, DD, DFF / 2, DFF, DFF, NTOK);
        if (l < LL - 1) {
            residrms_kernel<1><<<M, 256, 0, stream>>>(hb, pb0, pb1, mscale + l * DD,
                                                      x0b, rmix + (size_t)(l + 1) * 2 * DD, xnb);
        } else {
            residmask_kernel<<<(int)(NTOK / 4 / 256), 256, 0, stream>>>(
                hb, pb0, pb1, mscale + l * DD, nch, out);
        }
    }
}

// Round 21
// 767.517 us; speedup vs baseline: 1.1209x; 1.0173x over previous
//
#include <hip/hip_runtime.h>
#include <math.h>

// Problem constants (fixed by reference)
#define BB   4
#define SS   4096
#define DD   1024
#define HH   16
#define HDIM 64
#define CC   1024      // MAX_CHUNKS
#define DFF  4096
#define LL   4

static constexpr float F32_EPS = 1.1920928955078125e-07f;  // jnp.finfo(f32).eps

typedef __attribute__((ext_vector_type(8))) __bf16 bf16x8;
typedef __attribute__((ext_vector_type(4))) float  f32x4;

__device__ __forceinline__ uint f2bf(float f) {
    uint u = __float_as_uint(f);
    return (u + 0x7fffu + ((u >> 16) & 1u)) >> 16;   // RNE
}
__device__ __forceinline__ float bf2f(uint u) {
    return __uint_as_float(u << 16);
}

// direct global->LDS DMA, 16 bytes per lane; lds dest must be wave-uniform
__device__ __forceinline__ void gl_lds16(const ushort* g, ushort* l) {
    __builtin_amdgcn_global_load_lds(
        (const __attribute__((address_space(1))) unsigned int*)g,
        (__attribute__((address_space(3))) unsigned int*)l, 16, 0, 0);
}

// ---------------- per-layer mega-cast: all 5 weight mats f32 -> bf16 in one launch --------
__global__ __launch_bounds__(256) void castlayer_kernel(const float* __restrict__ Wq,
                                                        const float* __restrict__ Wk,
                                                        const float* __restrict__ Wv,
                                                        const float* __restrict__ Wo,
                                                        const float* __restrict__ fc,
                                                        const float* __restrict__ proj,
                                                        ushort* __restrict__ out) {
    int i = blockIdx.x * blockDim.x + threadIdx.x;      // 8-elem chunk id, 0..12M/8
    const int U = DD * DD / 8;                          // 131072
    const float* src;
    if (i < 3 * U) {
        src = (i < U ? Wq : (i < 2 * U ? Wk : Wv)) + (size_t)(i < U ? i : (i < 2*U ? i-U : i-2*U)) * 8;
    } else if (i < 4 * U) {
        src = Wo + (size_t)(i - 3 * U) * 8;
    } else if (i < 8 * U) {
        src = fc + (size_t)(i - 4 * U) * 8;
    } else {
        src = proj + (size_t)(i - 8 * U) * 8;
    }
    const float4* p = (const float4*)src;
    float4 a = p[0], b = p[1];
    uint4 o;
    o.x = f2bf(a.x) | (f2bf(a.y) << 16);
    o.y = f2bf(a.z) | (f2bf(a.w) << 16);
    o.z = f2bf(b.x) | (f2bf(b.y) << 16);
    o.w = f2bf(b.z) | (f2bf(b.w) << 16);
    *(uint4*)(out + (size_t)i * 8) = o;
}

// ---------------- RoPE tables ----------------
__global__ void rope_init_kernel(float* __restrict__ cosT, float* __restrict__ sinT) {
    int idx = blockIdx.x * blockDim.x + threadIdx.x;   // over CC*32
    int pos = idx >> 5;
    int i   = idx & 31;
    float inv = powf(10000.0f, -(float)i / 32.0f);
    float f = (float)pos * inv;
    cosT[idx] = cosf(f);
    sinT[idx] = sinf(f);
}

// ---------------- boundary scan -> chunk starts, num_chunks ----------------
__global__ __launch_bounds__(1024) void scan_kernel(const int* __restrict__ boundary,
                                                    int* __restrict__ starts,
                                                    int* __restrict__ nch) {
    __shared__ int tmp[1024];
    int b = blockIdx.x, t = threadIdx.x;
    int base = b * SS + t * 4;
    int v0 = boundary[base + 0], v1 = boundary[base + 1];
    int v2 = boundary[base + 2], v3 = boundary[base + 3];
    int p0 = v0, p1 = p0 + v1, p2 = p1 + v2, p3 = p2 + v3;
    tmp[t] = p3;
    __syncthreads();
    for (int off = 1; off < 1024; off <<= 1) {
        int add = (t >= off) ? tmp[t - off] : 0;
        __syncthreads();
        tmp[t] += add;
        __syncthreads();
    }
    int excl = tmp[t] - p3;
    if (v0) starts[b * (CC + 1) + (excl + p0 - 1)] = t * 4 + 0;
    if (v1) starts[b * (CC + 1) + (excl + p1 - 1)] = t * 4 + 1;
    if (v2) starts[b * (CC + 1) + (excl + p2 - 1)] = t * 4 + 2;
    if (v3) starts[b * (CC + 1) + (excl + p3 - 1)] = t * 4 + 3;
    int total = tmp[1023];
    if (t == 0) nch[b] = total;
    for (int c = t; c <= CC; c += 1024)
        if (c >= total) starts[b * (CC + 1) + c] = SS;
}

// ---------------- chunk means -> h (bf16) and x0 (bf16) ----------------
__global__ __launch_bounds__(256) void latents_kernel(const float* __restrict__ x,
                                                      const int* __restrict__ starts,
                                                      ushort* __restrict__ h,
                                                      ushort* __restrict__ x0) {
    int c = blockIdx.x, b = blockIdx.y, t = threadIdx.x;
    int s0 = starts[b * (CC + 1) + c];
    int s1 = starts[b * (CC + 1) + c + 1];
    float a0 = 0.f, a1 = 0.f, a2 = 0.f, a3 = 0.f;
    for (int r = s0; r < s1; ++r) {
        const float4 xv = *(const float4*)&x[((size_t)(b * SS + r)) * DD + t * 4];
        a0 += xv.x; a1 += xv.y; a2 += xv.z; a3 += xv.w;
    }
    float inv = (s1 > s0) ? 1.0f / (float)(s1 - s0) : 0.0f;
    a0 *= inv; a1 *= inv; a2 *= inv; a3 *= inv;
    size_t off = ((size_t)(b * CC + c)) * DD + t * 4;
    uint2 pk;
    pk.x = f2bf(a0) | (f2bf(a1) << 16);
    pk.y = f2bf(a2) | (f2bf(a3) << 16);
    *(uint2*)&h[off]  = pk;
    *(uint2*)&x0[off] = pk;
}

// ---------------- resid-mix + row RMS norm (layer-0 entry), bf16 h/x0 ----------------
__global__ __launch_bounds__(256) void rmsmix_kernel(const ushort* __restrict__ hin,
                                                     const ushort* __restrict__ x0,
                                                     const float* __restrict__ mix,
                                                     ushort* __restrict__ hout,
                                                     ushort* __restrict__ xnout) {
    int row = blockIdx.x, t = threadIdx.x;
    size_t off = (size_t)row * DD + t * 4;
    uint2 hu = *(const uint2*)&hin[off];
    float4 m0 = *(const float4*)&mix[t * 4];
    float4 m1 = *(const float4*)&mix[DD + t * 4];
    uint2 xv = *(const uint2*)&x0[off];
    float4 hv;
    hv.x = m0.x * bf2f(hu.x & 0xffff) + m1.x * bf2f(xv.x & 0xffff);
    hv.y = m0.y * bf2f(hu.x >> 16)    + m1.y * bf2f(xv.x >> 16);
    hv.z = m0.z * bf2f(hu.y & 0xffff) + m1.z * bf2f(xv.y & 0xffff);
    hv.w = m0.w * bf2f(hu.y >> 16)    + m1.w * bf2f(xv.y >> 16);
    float ss = hv.x * hv.x + hv.y * hv.y + hv.z * hv.z + hv.w * hv.w;
    for (int o = 32; o; o >>= 1) ss += __shfl_xor(ss, o);
    __shared__ float wsum[4];
    int lane = t & 63, wid = t >> 6;
    if (lane == 0) wsum[wid] = ss;
    __syncthreads();
    float tot = wsum[0] + wsum[1] + wsum[2] + wsum[3];
    float r = rsqrtf(tot * (1.0f / DD) + F32_EPS);
    uint2 ph;
    ph.x = f2bf(hv.x) | (f2bf(hv.y) << 16);
    ph.y = f2bf(hv.z) | (f2bf(hv.w) << 16);
    *(uint2*)&hout[off] = ph;
    uint2 pk;
    pk.x = f2bf(hv.x * r) | (f2bf(hv.y * r) << 16);
    pk.y = f2bf(hv.z * r) | (f2bf(hv.w * r) << 16);
    *(uint2*)&xnout[off] = pk;
}

// ---------------- fused: h += scale*(a0+a1); [h = m0*h+m1*x0]; xn = bf16(rms(h)) ---------
// h, a0/a1, x0 all bf16.
template <int HASMIX>
__global__ __launch_bounds__(256) void residrms_kernel(ushort* __restrict__ h,
                                                       const ushort* __restrict__ a0,
                                                       const ushort* __restrict__ a1,
                                                       const float* __restrict__ scale,
                                                       const ushort* __restrict__ x0,
                                                       const float* __restrict__ mix,
                                                       ushort* __restrict__ xnout) {
    int row = blockIdx.x, t = threadIdx.x;
    size_t off = (size_t)row * DD + t * 4;
    uint2 hu = *(const uint2*)&h[off];
    uint2 pa = *(const uint2*)&a0[off];
    uint2 pb = *(const uint2*)&a1[off];
    float4 sv = *(const float4*)&scale[t * 4];
    float4 hv;
    hv.x = bf2f(hu.x & 0xffff) + sv.x * (bf2f(pa.x & 0xffff) + bf2f(pb.x & 0xffff));
    hv.y = bf2f(hu.x >> 16)    + sv.y * (bf2f(pa.x >> 16)    + bf2f(pb.x >> 16));
    hv.z = bf2f(hu.y & 0xffff) + sv.z * (bf2f(pa.y & 0xffff) + bf2f(pb.y & 0xffff));
    hv.w = bf2f(hu.y >> 16)    + sv.w * (bf2f(pa.y >> 16)    + bf2f(pb.y >> 16));
    if (HASMIX) {
        float4 m0 = *(const float4*)&mix[t * 4];
        float4 m1 = *(const float4*)&mix[DD + t * 4];
        uint2 xv = *(const uint2*)&x0[off];
        hv.x = m0.x * hv.x + m1.x * bf2f(xv.x & 0xffff);
        hv.y = m0.y * hv.y + m1.y * bf2f(xv.x >> 16);
        hv.z = m0.z * hv.z + m1.z * bf2f(xv.y & 0xffff);
        hv.w = m0.w * hv.w + m1.w * bf2f(xv.y >> 16);
    }
    float ss = hv.x * hv.x + hv.y * hv.y + hv.z * hv.z + hv.w * hv.w;
    for (int o = 32; o; o >>= 1) ss += __shfl_xor(ss, o);
    __shared__ float wsum[4];
    int lane = t & 63, wid = t >> 6;
    if (lane == 0) wsum[wid] = ss;
    __syncthreads();
    float tot = wsum[0] + wsum[1] + wsum[2] + wsum[3];
    float r = rsqrtf(tot * (1.0f / DD) + F32_EPS);
    uint2 ph;
    ph.x = f2bf(hv.x) | (f2bf(hv.y) << 16);
    ph.y = f2bf(hv.z) | (f2bf(hv.w) << 16);
    *(uint2*)&h[off] = ph;
    uint2 pk;
    pk.x = f2bf(hv.x * r) | (f2bf(hv.y * r) << 16);
    pk.y = f2bf(hv.z * r) | (f2bf(hv.w * r) << 16);
    *(uint2*)&xnout[off] = pk;
}

// ---------------- bf16 MFMA GEMM, 2-phase double-buffered pipeline, 512 threads ----------
// 128x128 tile, BK=64, 8 waves in a 4M x 2N grid (per-wave output 32x64, acc[2][4]).
// XCD remap: 8m x 4n supertiles per XCD chunk (L2-resident A+W slabs, verified r16).
// EPI 0: bf16 partial store (split-K); EPI 1: relu^2 bf16; EPI 3: fused QKV+qknorm,
// with the v-third written DIRECTLY TRANSPOSED via post-loop LDS transpose (vtrans fused).
template <int EPI>
__global__ __launch_bounds__(512) void gemm_bf16(const ushort* __restrict__ A,
                                                 const ushort* __restrict__ W,
                                                 ushort* __restrict__ C0,
                                                 ushort* __restrict__ C1,
                                                 ushort* __restrict__ C2,
                                                 const float* __restrict__ cosT,
                                                 const float* __restrict__ sinT,
                                                 const float* __restrict__ gain,
                                                 int M, int N, int K, int lda, int ldw,
                                                 size_t partStride) {
    __shared__ __align__(16) ushort Als[2][128 * 64];
    __shared__ __align__(16) ushort Wls[2][128 * 64];
    const int tid  = threadIdx.x;
    const int wid  = tid >> 6, lane = tid & 63;
    const int wr   = wid >> 1, wc   = wid & 1;          // 4x2 wave grid
    const int l15  = lane & 15, lhi = lane >> 4;

    // XCD-aware remap (bijective; all call sites: gy%8==0, gx%4==0, G%8==0)
    const int gx = gridDim.x, gy = gridDim.y, gz = gridDim.z;
    int i = (blockIdx.z * gy + blockIdx.y) * gx + blockIdx.x;
    int G = gx * gy * gz;
    int v = (i & 7) * (G >> 3) + (i >> 3);
    const int SM = 8, SN = 4;
    int r0_ = v % (SM * SN);
    int s_  = v / (SM * SN);
    int mt  = (s_ % (gy / SM)) * SM + (r0_ % SM);
    int s2_ = s_ / (gy / SM);
    int nt  = (s2_ % (gx / SN)) * SN + (r0_ / SM);
    int zt  = s2_ / (gx / SN);
    const int mbase = mt * 128, nbase = nt * 128;

    A  += (size_t)zt * K;
    W  += (size_t)zt * K;
    C0 += (size_t)zt * partStride;

    const int srow8  = lane >> 3;                       // 0..7
    const int gchunk = ((lane & 7) ^ srow8) * 8;        // inverse-swizzled source chunk
    const ushort* Ag = A + (size_t)(mbase + wid * 16 + srow8) * lda + gchunk;
    const ushort* Wg = W + (size_t)(nbase + wid * 16 + srow8) * ldw + gchunk;
    const int ldsoff = (wid * 16) * 64;                 // wave-uniform LDS base offset

    f32x4 acc[2][4] = {};
    const int swz  = (l15 & 7) << 3;
    const int aoff = (wr * 32 + l15) * 64;
    const int woff = (wc * 64 + l15) * 64;

    auto STAGE = [&](ushort* Alb, ushort* Wlb, int kk) {
#pragma unroll
        for (int s = 0; s < 2; ++s) {
            gl_lds16(Ag + kk + (size_t)s * 8 * lda, Alb + ldsoff + s * 8 * 64);
            gl_lds16(Wg + kk + (size_t)s * 8 * ldw, Wlb + ldsoff + s * 8 * 64);
        }
    };
    auto COMPUTE = [&](const ushort* Ab, const ushort* Wb) {
#pragma unroll
        for (int ks = 0; ks < 2; ++ks) {
            const int fcol = (ks * 32 + lhi * 8) ^ swz;
            bf16x8 af[2], bfm[4];
#pragma unroll
            for (int m = 0; m < 2; ++m)
                af[m] = *(const bf16x8*)(Ab + aoff + m * 1024 + fcol);
#pragma unroll
            for (int n = 0; n < 4; ++n)
                bfm[n] = *(const bf16x8*)(Wb + woff + n * 1024 + fcol);
#pragma unroll
            for (int m = 0; m < 2; ++m)
#pragma unroll
                for (int n = 0; n < 4; ++n)
                    acc[m][n] = __builtin_amdgcn_mfma_f32_16x16x32_bf16(
                        af[m], bfm[n], acc[m][n], 0, 0, 0);
        }
    };

    STAGE(Als[0], Wls[0], 0);
    __syncthreads();
    for (int k0 = 0; k0 < K; k0 += 128) {
        if (k0 + 64 < K) STAGE(Als[1], Wls[1], k0 + 64);
        COMPUTE(Als[0], Wls[0]);
        __syncthreads();
        if (k0 + 128 < K) STAGE(Als[0], Wls[0], k0 + 128);
        COMPUTE(Als[1], Wls[1]);
        __syncthreads();
    }

    const int row0 = mbase + wr * 32 + lhi * 4;

    if (EPI == 3) {
        const int third = nbase >> 10;                  // 0=q, 1=k, 2=v
        const int bandbase = (nbase & 1023) + wc * 64;  // head band start in [0,1024)
        if (third == 2) {
            // --- fused V transpose: acc -> LDS T[d][token^sw] -> vt[(b*16+h)*64+d][token]
            // swizzle (co&15)<<3 spreads banks by (co&7)*4 -> <=2-way conflicts
            ushort* T = Als[0];                         // 2x(128*64) = 128*128 ushorts
#pragma unroll
            for (int m = 0; m < 2; ++m)
#pragma unroll
                for (int n = 0; n < 4; ++n) {
                    int co = wc * 64 + n * 16 + l15;    // local d   (0..127)
                    int cs = (co & 15) << 3;
#pragma unroll
                    for (int r = 0; r < 4; ++r) {
                        int ro = wr * 32 + m * 16 + lhi * 4 + r;   // local token
                        T[co * 128 + (ro ^ cs)] = (ushort)f2bf(acc[m][n][r]);
                    }
                }
            __syncthreads();
            const int batch = mbase >> 10;              // one batch per block (M-tile=128)
            const int cbase = mbase & 1023;
            const int hd0   = (nbase - 2048) >> 6;      // first head of this block
            const int co    = tid >> 2;                 // 0..127 (local d)
            const int tch   = (tid & 3) * 8;            // token chunk within 32
            const int csw   = (co & 15) << 3;
            size_t vrow = (size_t)((batch * HH + hd0 + (co >> 6)) * HDIM + (co & 63));
#pragma unroll
            for (int p = 0; p < 4; ++p) {
                int t0 = p * 32 + tch;
                int4 val = *(const int4*)&T[co * 128 + (t0 ^ csw)];
                *(int4*)&C2[vrow * CC + cbase + t0] = val;
            }
        } else {
            ushort* dst = (third == 0) ? C0 : C1;
            const int hd = bandbase >> 6;
            const float g = (third == 0) ? gain[hd] * 0.125f : 1.0f;
#pragma unroll
            for (int m = 0; m < 2; ++m)
#pragma unroll
                for (int r = 0; r < 4; ++r) {
                    int rr = row0 + m * 16 + r;
                    float v0 = acc[m][0][r], v1 = acc[m][1][r];
                    float v2 = acc[m][2][r], v3 = acc[m][3][r];
                    float ss = v0 * v0 + v1 * v1 + v2 * v2 + v3 * v3;
#pragma unroll
                    for (int off = 1; off < 16; off <<= 1) ss += __shfl_xor(ss, off);
                    float rn = rsqrtf(ss * (1.0f / HDIM) + F32_EPS);
                    v0 *= rn; v1 *= rn; v2 *= rn; v3 *= rn;
                    int c = rr & (CC - 1);
                    float c0 = cosT[c * 32 + l15],      s0 = sinT[c * 32 + l15];
                    float c1 = cosT[c * 32 + 16 + l15], s1 = sinT[c * 32 + 16 + l15];
                    float o0 = (v0 * c0 + v2 * s0) * g;
                    float o1 = (v1 * c1 + v3 * s1) * g;
                    float o2 = (v2 * c0 - v0 * s0) * g;
                    float o3 = (v3 * c1 - v1 * s1) * g;
                    size_t rbase = (size_t)rr * 1024 + bandbase;
                    dst[rbase + l15]      = (ushort)f2bf(o0);
                    dst[rbase + 16 + l15] = (ushort)f2bf(o1);
                    dst[rbase + 32 + l15] = (ushort)f2bf(o2);
                    dst[rbase + 48 + l15] = (ushort)f2bf(o3);
                }
        }
    } else {
        const int col0 = nbase + wc * 64 + l15;
#pragma unroll
        for (int m = 0; m < 2; ++m)
#pragma unroll
            for (int n = 0; n < 4; ++n) {
                int cc = col0 + n * 16;
#pragma unroll
                for (int r = 0; r < 4; ++r) {
                    int rr = row0 + m * 16 + r;
                    float v2 = acc[m][n][r];
                    if (EPI == 1) { v2 = fmaxf(v2, 0.0f); v2 = v2 * v2; }
                    C0[(size_t)rr * N + cc] = (ushort)f2bf(v2);
                }
            }
    }
}

// ---------------- bf16 MFMA causal flash attention: QBLK=128, KVBLK=64, 8 waves (512 thr),
// static-max softmax, double-buffered K/V LDS (ONE barrier per tile), T14 reg prefetch.
// qt remap balances causal work: qt = (b<2) ? 7-x : x, so co-resident block pairs
// (i, i+256) sum to a CONSTANT 18 tiles per CU (was 4..32 imbalance).
__global__ __launch_bounds__(512) void attn_mfma(const ushort* __restrict__ q,
                                                 const ushort* __restrict__ k,
                                                 const ushort* __restrict__ vt,
                                                 ushort* __restrict__ y,
                                                 const float* __restrict__ gain) {
    __shared__ __align__(16) ushort Qs[128 * 64];    // [qrow][d  ^ sw]
    __shared__ __align__(16) ushort Ks[2][64 * 64];  // [kv]  [d  ^ sw]
    __shared__ __align__(16) ushort VT[2][64 * 64];  // [d]   [kv ^ sw]
    __shared__ __align__(16) ushort Ps[128 * 64];    // [qrow][kv ^ sw] (wave-private rows)
    const int head = blockIdx.y, b = blockIdx.z;
    const int qt = (b < 2) ? (7 - blockIdx.x) : blockIdx.x;   // balanced causal remap
    const int tid = threadIdx.x;
    const int wid = tid >> 6, lane = tid & 63;    // 8 waves (512 threads), 16 q-rows each
    const int l15 = lane & 15, lhi = lane >> 4;
    const int wq0 = wid * 16;                     // 0..112
    const int qbase = qt * 128;
    const float mstat = 8.0f * fabsf(gain[head]); // static softmax max bound

    const int srow = tid >> 3;            // 0..63 (512 threads)
    const int scol = (tid & 7) * 8;       // 0..56 step 8

    // stage Q once (128 rows, 2 passes of 64 rows)
#pragma unroll
    for (int s = 0; s < 2; ++s) {
        int r = srow + s * 64;
        int4 t4 = *(const int4*)&q[((size_t)(b * CC + qbase + r)) * DD + head * HDIM + scol];
        *(int4*)&Qs[r * 64 + (scol ^ ((r & 7) << 3))] = t4;
    }

    f32x4 oacc[4] = {};
    float lpart[4] = {0.f, 0.f, 0.f, 0.f};

    const int NT = 2 * qt + 2;            // KV tiles of 64

    int4 kr, vr;
    auto LOADK = [&](int kt_) {
        kr = *(const int4*)&k[((size_t)(b * CC + kt_ * 64 + srow)) * DD + head * HDIM + scol];
        vr = *(const int4*)&vt[((size_t)((b * HH + head) * HDIM + srow)) * CC + kt_ * 64 + scol];
    };
    auto WRITEK = [&](int buf) {
        *(int4*)&Ks[buf][srow * 64 + (scol ^ ((srow & 7) << 3))] = kr;
        *(int4*)&VT[buf][srow * 64 + (scol ^ ((srow & 7) << 3))] = vr;
    };
    auto TILE = [&](int kt, int buf) {
        const ushort* Kb = Ks[buf];
        const ushort* Vb = VT[buf];
        f32x4 sac[4] = {};
        __builtin_amdgcn_s_setprio(1);
#pragma unroll
        for (int ks = 0; ks < 2; ++ks) {
            int dcol = ks * 32 + lhi * 8;
            int arow = wq0 + l15;
            bf16x8 af = *(const bf16x8*)&Qs[arow * 64 + (dcol ^ ((arow & 7) << 3))];
#pragma unroll
            for (int n = 0; n < 4; ++n) {
                int krow = n * 16 + l15;
                bf16x8 bfr = *(const bf16x8*)&Kb[krow * 64 + (dcol ^ ((krow & 7) << 3))];
                sac[n] = __builtin_amdgcn_mfma_f32_16x16x32_bf16(af, bfr, sac[n], 0, 0, 0);
            }
        }
        __builtin_amdgcn_s_setprio(0);

        if (kt >= 2 * qt) {               // diagonal-region tiles (last two)
            const int kb0 = kt * 64;
#pragma unroll
            for (int r = 0; r < 4; ++r) {
                int qrow_g = qbase + wq0 + lhi * 4 + r;
                float p0 = __expf(sac[0][r] - mstat);
                float p1 = __expf(sac[1][r] - mstat);
                float p2 = __expf(sac[2][r] - mstat);
                float p3 = __expf(sac[3][r] - mstat);
                if (kb0 + l15      > qrow_g) p0 = 0.f;
                if (kb0 + 16 + l15 > qrow_g) p1 = 0.f;
                if (kb0 + 32 + l15 > qrow_g) p2 = 0.f;
                if (kb0 + 48 + l15 > qrow_g) p3 = 0.f;
                lpart[r] += (p0 + p1) + (p2 + p3);
                int qrow_l = wq0 + lhi * 4 + r;
                int pb = qrow_l * 64, sw = (qrow_l & 7) << 3;
                Ps[pb + ((l15)      ^ sw)] = (ushort)f2bf(p0);
                Ps[pb + ((16 + l15) ^ sw)] = (ushort)f2bf(p1);
                Ps[pb + ((32 + l15) ^ sw)] = (ushort)f2bf(p2);
                Ps[pb + ((48 + l15) ^ sw)] = (ushort)f2bf(p3);
            }
        } else {
#pragma unroll
            for (int r = 0; r < 4; ++r) {
                float p0 = __expf(sac[0][r] - mstat);
                float p1 = __expf(sac[1][r] - mstat);
                float p2 = __expf(sac[2][r] - mstat);
                float p3 = __expf(sac[3][r] - mstat);
                lpart[r] += (p0 + p1) + (p2 + p3);
                int qrow_l = wq0 + lhi * 4 + r;
                int pb = qrow_l * 64, sw = (qrow_l & 7) << 3;
                Ps[pb + ((l15)      ^ sw)] = (ushort)f2bf(p0);
                Ps[pb + ((16 + l15) ^ sw)] = (ushort)f2bf(p1);
                Ps[pb + ((32 + l15) ^ sw)] = (ushort)f2bf(p2);
                Ps[pb + ((48 + l15) ^ sw)] = (ushort)f2bf(p3);
            }
        }

        __builtin_amdgcn_s_setprio(1);
#pragma unroll
        for (int ks = 0; ks < 2; ++ks) {
            int kcol = ks * 32 + lhi * 8;
            int arow = wq0 + l15;
            bf16x8 pf = *(const bf16x8*)&Ps[arow * 64 + (kcol ^ ((arow & 7) << 3))];
#pragma unroll
            for (int n = 0; n < 4; ++n) {
                int vrow = n * 16 + l15;
                bf16x8 vf = *(const bf16x8*)&Vb[vrow * 64 + (kcol ^ ((vrow & 7) << 3))];
                oacc[n] = __builtin_amdgcn_mfma_f32_16x16x32_bf16(pf, vf, oacc[n], 0, 0, 0);
            }
        }
        __builtin_amdgcn_s_setprio(0);
    };

    // Double-buffered pipeline: ONE barrier per tile.
    LOADK(0);
    WRITEK(0);
    for (int kt = 0; kt < NT; ++kt) {
        if (kt + 1 < NT) LOADK(kt + 1);   // global loads fly under TILE(kt)
        __syncthreads();                  // buf[kt&1] writes visible to all waves
        TILE(kt, kt & 1);
        if (kt + 1 < NT) WRITEK((kt + 1) & 1);
    }

    // single deferred row-sum reduce (16 lanes per row), then divide + store
#pragma unroll
    for (int r = 0; r < 4; ++r) {
        float ls = lpart[r];
#pragma unroll
        for (int off = 1; off < 16; off <<= 1) ls += __shfl_xor(ls, off);
        float inv = 1.0f / ls;
        int qrow_g = qbase + wq0 + lhi * 4 + r;
        size_t base = ((size_t)(b * CC + qrow_g)) * DD + head * HDIM;
#pragma unroll
        for (int n = 0; n < 4; ++n)
            y[base + n * 16 + l15] = (ushort)f2bf(oacc[n][r] * inv);
    }
}

// ---------------- final: out = (h + scale*(a0+a1)) * valid  (h, partials bf16) ------------
__global__ void residmask_kernel(const ushort* __restrict__ h, const ushort* __restrict__ a0,
                                 const ushort* __restrict__ a1,
                                 const float* __restrict__ scale,
                                 const int* __restrict__ nch,
                                 float* __restrict__ out) {
    int idx = blockIdx.x * blockDim.x + threadIdx.x;   // per float4
    size_t off = (size_t)idx * 4;
    int c = (idx >> 8) & (CC - 1);
    int b = idx >> 18;
    uint2 hu = *(const uint2*)&h[off];
    uint2 pa = *(const uint2*)&a0[off];
    uint2 pb = *(const uint2*)&a1[off];
    float4 sv = *(const float4*)&scale[(idx & 255) * 4];
    float4 hv;
    hv.x = bf2f(hu.x & 0xffff) + sv.x * (bf2f(pa.x & 0xffff) + bf2f(pb.x & 0xffff));
    hv.y = bf2f(hu.x >> 16)    + sv.y * (bf2f(pa.x >> 16)    + bf2f(pb.x >> 16));
    hv.z = bf2f(hu.y & 0xffff) + sv.z * (bf2f(pa.y & 0xffff) + bf2f(pb.y & 0xffff));
    hv.w = bf2f(hu.y >> 16)    + sv.w * (bf2f(pa.y >> 16)    + bf2f(pb.y >> 16));
    if (c >= nch[b]) hv = make_float4(0.f, 0.f, 0.f, 0.f);
    *(float4*)&out[off] = hv;
}

extern "C" void kernel_launch(void* const* d_in, const int* in_sizes, int n_in,
                              void* d_out, int out_size, void* d_ws, size_t ws_size,
                              hipStream_t stream) {
    const float* x        = (const float*)d_in[0];
    const int*   boundary = (const int*)d_in[1];
    const float* Wq       = (const float*)d_in[2];
    const float* Wk       = (const float*)d_in[3];
    const float* Wv       = (const float*)d_in[4];
    const float* Wo       = (const float*)d_in[5];
    const float* qg       = (const float*)d_in[6];
    const float* fcw      = (const float*)d_in[7];
    const float* projw    = (const float*)d_in[8];
    const float* ascale   = (const float*)d_in[9];
    const float* mscale   = (const float*)d_in[10];
    const float* rmix     = (const float*)d_in[11];
    float* out = (float*)d_out;

    const size_t NTOK = (size_t)BB * CC * DD;           // 4M elems
    const size_t NHID = (size_t)BB * CC * DFF;          // 16M elems
    const size_t D2   = (size_t)DD * DD;                // 1M elems

    ushort* hb   = (ushort*)d_ws;                       // 4M bf16 residual h
    ushort* x0b  = hb + NTOK;                           // 4M bf16
    ushort* pb0  = x0b + NTOK;                          // 4M bf16 split-K partial 0
    ushort* pb1  = pb0 + NTOK;                          // 4M bf16 split-K partial 1
    ushort* xnb  = pb1 + NTOK;                          // 4M bf16
    ushort* ybf  = xnb + NTOK;                          // 4M bf16
    ushort* hidb = ybf + NTOK;                          // 16M bf16 (q/k during attn)
    ushort* wbuf = hidb + NHID;                         // 16M bf16 weights (12M used)
    ushort* vtb  = wbuf + NHID;                         // 4M bf16 (V transposed, direct)
    float*  cosT = (float*)(vtb + NTOK);
    float*  sinT = cosT + (size_t)CC * 32;
    int*    starts = (int*)(sinT + (size_t)CC * 32);
    int*    nch    = starts + BB * (CC + 1);

    ushort* qbb = hidb;                  // bf16 q (normed+RoPE'd by fused epilogue)
    ushort* kbb = hidb + NTOK;           // bf16 k

    ushort* wqkv = wbuf;                 // [0, 3M)
    ushort* wwo  = wbuf + 3 * D2;        // [3M, 4M)
    ushort* wfc  = wbuf + 4 * D2;        // [4M, 8M)
    ushort* wpj  = wbuf + 8 * D2;        // [8M, 12M)

    const int M = BB * CC;  // 4096 rows
    const int CASTL = (int)(12 * D2 / 8 / 256);         // 6144 blocks

    rope_init_kernel<<<CC * 32 / 256, 256, 0, stream>>>(cosT, sinT);
    scan_kernel<<<BB, 1024, 0, stream>>>(boundary, starts, nch);
    latents_kernel<<<dim3(CC, BB), 256, 0, stream>>>(x, starts, hb, x0b);
    rmsmix_kernel<<<M, 256, 0, stream>>>(hb, x0b, rmix, hb, xnb);   // layer-0 entry

    for (int l = 0; l < LL; ++l) {
        // one mega-cast for all this layer's weights
        castlayer_kernel<<<CASTL, 256, 0, stream>>>(Wq + l * D2, Wk + l * D2, Wv + l * D2,
                                                    Wo + l * D2,
                                                    fcw + (size_t)l * DFF * DD,
                                                    projw + (size_t)l * DD * DFF, wbuf);
        // fused QKV + qknorm epilogue; v written directly transposed into vtb
        gemm_bf16<3><<<dim3(3 * DD / 128, M / 128, 1), 512, 0, stream>>>(
            xnb, wqkv, qbb, kbb, vtb, cosT, sinT, qg + l * HH, M, 3 * DD, DD, DD, DD, 0);
        // MFMA attention -> ybf (QBLK=128, KVBLK=64, dbuf, balanced qt remap)
        attn_mfma<<<dim3(8, HH, BB), 512, 0, stream>>>(qbb, kbb, vtb, ybf, qg + l * HH);
        // a = y @ Wo^T, split-K=2 -> bf16 partials pb0,pb1; fused resid+rms -> xnb
        gemm_bf16<0><<<dim3(DD / 128, M / 128, 2), 512, 0, stream>>>(
            ybf, wwo, pb0, nullptr, nullptr, nullptr, nullptr, nullptr,
            M, DD, DD / 2, DD, DD, NTOK);
        residrms_kernel<0><<<M, 256, 0, stream>>>(hb, pb0, pb1, ascale + l * DD,
                                                  nullptr, nullptr, xnb);
        // MLP: fc (relu^2, bf16) then proj split-K=2 (bf16 partials)
        gemm_bf16<1><<<dim3(DFF / 128, M / 128, 1), 512, 0, stream>>>(
            xnb, wfc, hidb, nullptr, nullptr, nullptr, nullptr, nullptr,
            M, DFF, DD, DD, DD, 0);
        gemm_bf16<0><<<dim3(DD / 128, M / 128, 2), 512, 0, stream>>>(
            hidb, wpj, pb0, nullptr, nullptr, nullptr, nullptr, nullptr,
            M, DD, DFF / 2, DFF, DFF, NTOK);
        if (l < LL - 1) {
            residrms_kernel<1><<<M, 256, 0, stream>>>(hb, pb0, pb1, mscale + l * DD,
                                                      x0b, rmix + (size_t)(l + 1) * 2 * DD, xnb);
        } else {
            residmask_kernel<<<(int)(NTOK / 4 / 256), 256, 0, stream>>>(
                hb, pb0, pb1, mscale + l * DD, nch, out);
        }
    }
}

// Round 22
// 757.251 us; speedup vs baseline: 1.1361x; 1.0136x over previous
//
#include <hip/hip_runtime.h>
#include <math.h>

// Problem constants (fixed by reference)
#define BB   4
#define SS   4096
#define DD   1024
#define HH   16
#define HDIM 64
#define CC   1024      // MAX_CHUNKS
#define DFF  4096
#define LL   4

static constexpr float F32_EPS = 1.1920928955078125e-07f;  // jnp.finfo(f32).eps

typedef __attribute__((ext_vector_type(8))) __bf16 bf16x8;
typedef __attribute__((ext_vector_type(4))) float  f32x4;

__device__ __forceinline__ uint f2bf(float f) {
    uint u = __float_as_uint(f);
    return (u + 0x7fffu + ((u >> 16) & 1u)) >> 16;   // RNE
}
__device__ __forceinline__ float bf2f(uint u) {
    return __uint_as_float(u << 16);
}

// direct global->LDS DMA, 16 bytes per lane; lds dest must be wave-uniform
__device__ __forceinline__ void gl_lds16(const ushort* g, ushort* l) {
    __builtin_amdgcn_global_load_lds(
        (const __attribute__((address_space(1))) unsigned int*)g,
        (__attribute__((address_space(3))) unsigned int*)l, 16, 0, 0);
}

// ---------------- per-layer mega-cast: all 5 weight mats f32 -> bf16 in one launch --------
__global__ __launch_bounds__(256) void castlayer_kernel(const float* __restrict__ Wq,
                                                        const float* __restrict__ Wk,
                                                        const float* __restrict__ Wv,
                                                        const float* __restrict__ Wo,
                                                        const float* __restrict__ fc,
                                                        const float* __restrict__ proj,
                                                        ushort* __restrict__ out) {
    int i = blockIdx.x * blockDim.x + threadIdx.x;      // 8-elem chunk id, 0..12M/8
    const int U = DD * DD / 8;                          // 131072
    const float* src;
    if (i < 3 * U) {
        src = (i < U ? Wq : (i < 2 * U ? Wk : Wv)) + (size_t)(i < U ? i : (i < 2*U ? i-U : i-2*U)) * 8;
    } else if (i < 4 * U) {
        src = Wo + (size_t)(i - 3 * U) * 8;
    } else if (i < 8 * U) {
        src = fc + (size_t)(i - 4 * U) * 8;
    } else {
        src = proj + (size_t)(i - 8 * U) * 8;
    }
    const float4* p = (const float4*)src;
    float4 a = p[0], b = p[1];
    uint4 o;
    o.x = f2bf(a.x) | (f2bf(a.y) << 16);
    o.y = f2bf(a.z) | (f2bf(a.w) << 16);
    o.z = f2bf(b.x) | (f2bf(b.y) << 16);
    o.w = f2bf(b.z) | (f2bf(b.w) << 16);
    *(uint4*)(out + (size_t)i * 8) = o;
}

// ---------------- RoPE tables ----------------
__global__ void rope_init_kernel(float* __restrict__ cosT, float* __restrict__ sinT) {
    int idx = blockIdx.x * blockDim.x + threadIdx.x;   // over CC*32
    int pos = idx >> 5;
    int i   = idx & 31;
    float inv = powf(10000.0f, -(float)i / 32.0f);
    float f = (float)pos * inv;
    cosT[idx] = cosf(f);
    sinT[idx] = sinf(f);
}

// ---------------- boundary scan -> chunk starts, num_chunks ----------------
__global__ __launch_bounds__(1024) void scan_kernel(const int* __restrict__ boundary,
                                                    int* __restrict__ starts,
                                                    int* __restrict__ nch) {
    __shared__ int tmp[1024];
    int b = blockIdx.x, t = threadIdx.x;
    int base = b * SS + t * 4;
    int v0 = boundary[base + 0], v1 = boundary[base + 1];
    int v2 = boundary[base + 2], v3 = boundary[base + 3];
    int p0 = v0, p1 = p0 + v1, p2 = p1 + v2, p3 = p2 + v3;
    tmp[t] = p3;
    __syncthreads();
    for (int off = 1; off < 1024; off <<= 1) {
        int add = (t >= off) ? tmp[t - off] : 0;
        __syncthreads();
        tmp[t] += add;
        __syncthreads();
    }
    int excl = tmp[t] - p3;
    if (v0) starts[b * (CC + 1) + (excl + p0 - 1)] = t * 4 + 0;
    if (v1) starts[b * (CC + 1) + (excl + p1 - 1)] = t * 4 + 1;
    if (v2) starts[b * (CC + 1) + (excl + p2 - 1)] = t * 4 + 2;
    if (v3) starts[b * (CC + 1) + (excl + p3 - 1)] = t * 4 + 3;
    int total = tmp[1023];
    if (t == 0) nch[b] = total;
    for (int c = t; c <= CC; c += 1024)
        if (c >= total) starts[b * (CC + 1) + c] = SS;
}

// ---------------- chunk means -> h (bf16) and x0 (bf16) ----------------
__global__ __launch_bounds__(256) void latents_kernel(const float* __restrict__ x,
                                                      const int* __restrict__ starts,
                                                      ushort* __restrict__ h,
                                                      ushort* __restrict__ x0) {
    int c = blockIdx.x, b = blockIdx.y, t = threadIdx.x;
    int s0 = starts[b * (CC + 1) + c];
    int s1 = starts[b * (CC + 1) + c + 1];
    float a0 = 0.f, a1 = 0.f, a2 = 0.f, a3 = 0.f;
    for (int r = s0; r < s1; ++r) {
        const float4 xv = *(const float4*)&x[((size_t)(b * SS + r)) * DD + t * 4];
        a0 += xv.x; a1 += xv.y; a2 += xv.z; a3 += xv.w;
    }
    float inv = (s1 > s0) ? 1.0f / (float)(s1 - s0) : 0.0f;
    a0 *= inv; a1 *= inv; a2 *= inv; a3 *= inv;
    size_t off = ((size_t)(b * CC + c)) * DD + t * 4;
    uint2 pk;
    pk.x = f2bf(a0) | (f2bf(a1) << 16);
    pk.y = f2bf(a2) | (f2bf(a3) << 16);
    *(uint2*)&h[off]  = pk;
    *(uint2*)&x0[off] = pk;
}

// ---------------- resid-mix + row RMS norm (layer-0 entry), bf16 h/x0 ----------------
__global__ __launch_bounds__(256) void rmsmix_kernel(const ushort* __restrict__ hin,
                                                     const ushort* __restrict__ x0,
                                                     const float* __restrict__ mix,
                                                     ushort* __restrict__ hout,
                                                     ushort* __restrict__ xnout) {
    int row = blockIdx.x, t = threadIdx.x;
    size_t off = (size_t)row * DD + t * 4;
    uint2 hu = *(const uint2*)&hin[off];
    float4 m0 = *(const float4*)&mix[t * 4];
    float4 m1 = *(const float4*)&mix[DD + t * 4];
    uint2 xv = *(const uint2*)&x0[off];
    float4 hv;
    hv.x = m0.x * bf2f(hu.x & 0xffff) + m1.x * bf2f(xv.x & 0xffff);
    hv.y = m0.y * bf2f(hu.x >> 16)    + m1.y * bf2f(xv.x >> 16);
    hv.z = m0.z * bf2f(hu.y & 0xffff) + m1.z * bf2f(xv.y & 0xffff);
    hv.w = m0.w * bf2f(hu.y >> 16)    + m1.w * bf2f(xv.y >> 16);
    float ss = hv.x * hv.x + hv.y * hv.y + hv.z * hv.z + hv.w * hv.w;
    for (int o = 32; o; o >>= 1) ss += __shfl_xor(ss, o);
    __shared__ float wsum[4];
    int lane = t & 63, wid = t >> 6;
    if (lane == 0) wsum[wid] = ss;
    __syncthreads();
    float tot = wsum[0] + wsum[1] + wsum[2] + wsum[3];
    float r = rsqrtf(tot * (1.0f / DD) + F32_EPS);
    uint2 ph;
    ph.x = f2bf(hv.x) | (f2bf(hv.y) << 16);
    ph.y = f2bf(hv.z) | (f2bf(hv.w) << 16);
    *(uint2*)&hout[off] = ph;
    uint2 pk;
    pk.x = f2bf(hv.x * r) | (f2bf(hv.y * r) << 16);
    pk.y = f2bf(hv.z * r) | (f2bf(hv.w * r) << 16);
    *(uint2*)&xnout[off] = pk;
}

// ---------------- fused: h += scale*(a0+a1); [h = m0*h+m1*x0]; xn = bf16(rms(h)) ---------
// h, a0/a1, x0 all bf16.
template <int HASMIX>
__global__ __launch_bounds__(256) void residrms_kernel(ushort* __restrict__ h,
                                                       const ushort* __restrict__ a0,
                                                       const ushort* __restrict__ a1,
                                                       const float* __restrict__ scale,
                                                       const ushort* __restrict__ x0,
                                                       const float* __restrict__ mix,
                                                       ushort* __restrict__ xnout) {
    int row = blockIdx.x, t = threadIdx.x;
    size_t off = (size_t)row * DD + t * 4;
    uint2 hu = *(const uint2*)&h[off];
    uint2 pa = *(const uint2*)&a0[off];
    uint2 pb = *(const uint2*)&a1[off];
    float4 sv = *(const float4*)&scale[t * 4];
    float4 hv;
    hv.x = bf2f(hu.x & 0xffff) + sv.x * (bf2f(pa.x & 0xffff) + bf2f(pb.x & 0xffff));
    hv.y = bf2f(hu.x >> 16)    + sv.y * (bf2f(pa.x >> 16)    + bf2f(pb.x >> 16));
    hv.z = bf2f(hu.y & 0xffff) + sv.z * (bf2f(pa.y & 0xffff) + bf2f(pb.y & 0xffff));
    hv.w = bf2f(hu.y >> 16)    + sv.w * (bf2f(pa.y >> 16)    + bf2f(pb.y >> 16));
    if (HASMIX) {
        float4 m0 = *(const float4*)&mix[t * 4];
        float4 m1 = *(const float4*)&mix[DD + t * 4];
        uint2 xv = *(const uint2*)&x0[off];
        hv.x = m0.x * hv.x + m1.x * bf2f(xv.x & 0xffff);
        hv.y = m0.y * hv.y + m1.y * bf2f(xv.x >> 16);
        hv.z = m0.z * hv.z + m1.z * bf2f(xv.y & 0xffff);
        hv.w = m0.w * hv.w + m1.w * bf2f(xv.y >> 16);
    }
    float ss = hv.x * hv.x + hv.y * hv.y + hv.z * hv.z + hv.w * hv.w;
    for (int o = 32; o; o >>= 1) ss += __shfl_xor(ss, o);
    __shared__ float wsum[4];
    int lane = t & 63, wid = t >> 6;
    if (lane == 0) wsum[wid] = ss;
    __syncthreads();
    float tot = wsum[0] + wsum[1] + wsum[2] + wsum[3];
    float r = rsqrtf(tot * (1.0f / DD) + F32_EPS);
    uint2 ph;
    ph.x = f2bf(hv.x) | (f2bf(hv.y) << 16);
    ph.y = f2bf(hv.z) | (f2bf(hv.w) << 16);
    *(uint2*)&h[off] = ph;
    uint2 pk;
    pk.x = f2bf(hv.x * r) | (f2bf(hv.y * r) << 16);
    pk.y = f2bf(hv.z * r) | (f2bf(hv.w * r) << 16);
    *(uint2*)&xnout[off] = pk;
}

// ---------------- bf16 MFMA GEMM, 2-phase double-buffered pipeline, 512 threads ----------
// 128x128 tile, BK=64, 8 waves in a 4M x 2N grid (per-wave output 32x64, acc[2][4]).
// XCD remap: 8m x 4n supertiles per XCD chunk (L2-resident A+W slabs, verified r16).
// EPI 0: bf16 partial store (split-K); EPI 1: relu^2 bf16; EPI 3: fused QKV+qknorm,
// with the v-third written DIRECTLY TRANSPOSED via post-loop LDS transpose (vtrans fused).
template <int EPI>
__global__ __launch_bounds__(512) void gemm_bf16(const ushort* __restrict__ A,
                                                 const ushort* __restrict__ W,
                                                 ushort* __restrict__ C0,
                                                 ushort* __restrict__ C1,
                                                 ushort* __restrict__ C2,
                                                 const float* __restrict__ cosT,
                                                 const float* __restrict__ sinT,
                                                 const float* __restrict__ gain,
                                                 int M, int N, int K, int lda, int ldw,
                                                 size_t partStride) {
    __shared__ __align__(16) ushort Als[2][128 * 64];
    __shared__ __align__(16) ushort Wls[2][128 * 64];
    const int tid  = threadIdx.x;
    const int wid  = tid >> 6, lane = tid & 63;
    const int wr   = wid >> 1, wc   = wid & 1;          // 4x2 wave grid
    const int l15  = lane & 15, lhi = lane >> 4;

    // XCD-aware remap (bijective; all call sites: gy%8==0, gx%4==0, G%8==0)
    const int gx = gridDim.x, gy = gridDim.y, gz = gridDim.z;
    int i = (blockIdx.z * gy + blockIdx.y) * gx + blockIdx.x;
    int G = gx * gy * gz;
    int v = (i & 7) * (G >> 3) + (i >> 3);
    const int SM = 8, SN = 4;
    int r0_ = v % (SM * SN);
    int s_  = v / (SM * SN);
    int mt  = (s_ % (gy / SM)) * SM + (r0_ % SM);
    int s2_ = s_ / (gy / SM);
    int nt  = (s2_ % (gx / SN)) * SN + (r0_ / SM);
    int zt  = s2_ / (gx / SN);
    const int mbase = mt * 128, nbase = nt * 128;

    A  += (size_t)zt * K;
    W  += (size_t)zt * K;
    C0 += (size_t)zt * partStride;

    const int srow8  = lane >> 3;                       // 0..7
    const int gchunk = ((lane & 7) ^ srow8) * 8;        // inverse-swizzled source chunk
    const ushort* Ag = A + (size_t)(mbase + wid * 16 + srow8) * lda + gchunk;
    const ushort* Wg = W + (size_t)(nbase + wid * 16 + srow8) * ldw + gchunk;
    const int ldsoff = (wid * 16) * 64;                 // wave-uniform LDS base offset

    f32x4 acc[2][4] = {};
    const int swz  = (l15 & 7) << 3;
    const int aoff = (wr * 32 + l15) * 64;
    const int woff = (wc * 64 + l15) * 64;

    auto STAGE = [&](ushort* Alb, ushort* Wlb, int kk) {
#pragma unroll
        for (int s = 0; s < 2; ++s) {
            gl_lds16(Ag + kk + (size_t)s * 8 * lda, Alb + ldsoff + s * 8 * 64);
            gl_lds16(Wg + kk + (size_t)s * 8 * ldw, Wlb + ldsoff + s * 8 * 64);
        }
    };
    auto COMPUTE = [&](const ushort* Ab, const ushort* Wb) {
#pragma unroll
        for (int ks = 0; ks < 2; ++ks) {
            const int fcol = (ks * 32 + lhi * 8) ^ swz;
            bf16x8 af[2], bfm[4];
#pragma unroll
            for (int m = 0; m < 2; ++m)
                af[m] = *(const bf16x8*)(Ab + aoff + m * 1024 + fcol);
#pragma unroll
            for (int n = 0; n < 4; ++n)
                bfm[n] = *(const bf16x8*)(Wb + woff + n * 1024 + fcol);
#pragma unroll
            for (int m = 0; m < 2; ++m)
#pragma unroll
                for (int n = 0; n < 4; ++n)
                    acc[m][n] = __builtin_amdgcn_mfma_f32_16x16x32_bf16(
                        af[m], bfm[n], acc[m][n], 0, 0, 0);
        }
    };

    STAGE(Als[0], Wls[0], 0);
    __syncthreads();
    for (int k0 = 0; k0 < K; k0 += 128) {
        if (k0 + 64 < K) STAGE(Als[1], Wls[1], k0 + 64);
        COMPUTE(Als[0], Wls[0]);
        __syncthreads();
        if (k0 + 128 < K) STAGE(Als[0], Wls[0], k0 + 128);
        COMPUTE(Als[1], Wls[1]);
        __syncthreads();
    }

    const int row0 = mbase + wr * 32 + lhi * 4;

    if (EPI == 3) {
        const int third = nbase >> 10;                  // 0=q, 1=k, 2=v
        const int bandbase = (nbase & 1023) + wc * 64;  // head band start in [0,1024)
        if (third == 2) {
            // --- fused V transpose: acc -> LDS T[d][token^sw] -> vt[(b*16+h)*64+d][token]
            // swizzle (co&15)<<3 spreads banks by (co&7)*4 -> <=2-way conflicts
            ushort* T = Als[0];                         // 2x(128*64) = 128*128 ushorts
#pragma unroll
            for (int m = 0; m < 2; ++m)
#pragma unroll
                for (int n = 0; n < 4; ++n) {
                    int co = wc * 64 + n * 16 + l15;    // local d   (0..127)
                    int cs = (co & 15) << 3;
#pragma unroll
                    for (int r = 0; r < 4; ++r) {
                        int ro = wr * 32 + m * 16 + lhi * 4 + r;   // local token
                        T[co * 128 + (ro ^ cs)] = (ushort)f2bf(acc[m][n][r]);
                    }
                }
            __syncthreads();
            const int batch = mbase >> 10;              // one batch per block (M-tile=128)
            const int cbase = mbase & 1023;
            const int hd0   = (nbase - 2048) >> 6;      // first head of this block
            const int co    = tid >> 2;                 // 0..127 (local d)
            const int tch   = (tid & 3) * 8;            // token chunk within 32
            const int csw   = (co & 15) << 3;
            size_t vrow = (size_t)((batch * HH + hd0 + (co >> 6)) * HDIM + (co & 63));
#pragma unroll
            for (int p = 0; p < 4; ++p) {
                int t0 = p * 32 + tch;
                int4 val = *(const int4*)&T[co * 128 + (t0 ^ csw)];
                *(int4*)&C2[vrow * CC + cbase + t0] = val;
            }
        } else {
            ushort* dst = (third == 0) ? C0 : C1;
            const int hd = bandbase >> 6;
            const float g = (third == 0) ? gain[hd] * 0.125f : 1.0f;
#pragma unroll
            for (int m = 0; m < 2; ++m)
#pragma unroll
                for (int r = 0; r < 4; ++r) {
                    int rr = row0 + m * 16 + r;
                    float v0 = acc[m][0][r], v1 = acc[m][1][r];
                    float v2 = acc[m][2][r], v3 = acc[m][3][r];
                    float ss = v0 * v0 + v1 * v1 + v2 * v2 + v3 * v3;
#pragma unroll
                    for (int off = 1; off < 16; off <<= 1) ss += __shfl_xor(ss, off);
                    float rn = rsqrtf(ss * (1.0f / HDIM) + F32_EPS);
                    v0 *= rn; v1 *= rn; v2 *= rn; v3 *= rn;
                    int c = rr & (CC - 1);
                    float c0 = cosT[c * 32 + l15],      s0 = sinT[c * 32 + l15];
                    float c1 = cosT[c * 32 + 16 + l15], s1 = sinT[c * 32 + 16 + l15];
                    float o0 = (v0 * c0 + v2 * s0) * g;
                    float o1 = (v1 * c1 + v3 * s1) * g;
                    float o2 = (v2 * c0 - v0 * s0) * g;
                    float o3 = (v3 * c1 - v1 * s1) * g;
                    size_t rbase = (size_t)rr * 1024 + bandbase;
                    dst[rbase + l15]      = (ushort)f2bf(o0);
                    dst[rbase + 16 + l15] = (ushort)f2bf(o1);
                    dst[rbase + 32 + l15] = (ushort)f2bf(o2);
                    dst[rbase + 48 + l15] = (ushort)f2bf(o3);
                }
        }
    } else {
        const int col0 = nbase + wc * 64 + l15;
#pragma unroll
        for (int m = 0; m < 2; ++m)
#pragma unroll
            for (int n = 0; n < 4; ++n) {
                int cc = col0 + n * 16;
#pragma unroll
                for (int r = 0; r < 4; ++r) {
                    int rr = row0 + m * 16 + r;
                    float v2 = acc[m][n][r];
                    if (EPI == 1) { v2 = fmaxf(v2, 0.0f); v2 = v2 * v2; }
                    C0[(size_t)rr * N + cc] = (ushort)f2bf(v2);
                }
            }
    }
}

// ---------------- bf16 MFMA causal flash attention: QBLK=128, KVBLK=64, 8 waves (512 thr),
// static-max softmax, double-buffered K/V LDS (ONE barrier per tile), T14 reg prefetch.
// qt remap balances causal work: qt = (b<2) ? 7-x : x, so co-resident block pairs
// (i, i+256) sum to a CONSTANT 18 tiles per CU (was 4..32 imbalance).
__global__ __launch_bounds__(512) void attn_mfma(const ushort* __restrict__ q,
                                                 const ushort* __restrict__ k,
                                                 const ushort* __restrict__ vt,
                                                 ushort* __restrict__ y,
                                                 const float* __restrict__ gain) {
    __shared__ __align__(16) ushort Qs[128 * 64];    // [qrow][d  ^ sw]
    __shared__ __align__(16) ushort Ks[2][64 * 64];  // [kv]  [d  ^ sw]
    __shared__ __align__(16) ushort VT[2][64 * 64];  // [d]   [kv ^ sw]
    __shared__ __align__(16) ushort Ps[128 * 64];    // [qrow][kv ^ sw] (wave-private rows)
    const int head = blockIdx.y, b = blockIdx.z;
    const int qt = (b < 2) ? (7 - blockIdx.x) : blockIdx.x;   // balanced causal remap
    const int tid = threadIdx.x;
    const int wid = tid >> 6, lane = tid & 63;    // 8 waves (512 threads), 16 q-rows each
    const int l15 = lane & 15, lhi = lane >> 4;
    const int wq0 = wid * 16;                     // 0..112
    const int qbase = qt * 128;
    const float mstat = 8.0f * fabsf(gain[head]); // static softmax max bound

    const int srow = tid >> 3;            // 0..63 (512 threads)
    const int scol = (tid & 7) * 8;       // 0..56 step 8

    // stage Q once (128 rows, 2 passes of 64 rows)
#pragma unroll
    for (int s = 0; s < 2; ++s) {
        int r = srow + s * 64;
        int4 t4 = *(const int4*)&q[((size_t)(b * CC + qbase + r)) * DD + head * HDIM + scol];
        *(int4*)&Qs[r * 64 + (scol ^ ((r & 7) << 3))] = t4;
    }

    f32x4 oacc[4] = {};
    float lpart[4] = {0.f, 0.f, 0.f, 0.f};

    const int NT = 2 * qt + 2;            // KV tiles of 64

    int4 kr, vr;
    auto LOADK = [&](int kt_) {
        kr = *(const int4*)&k[((size_t)(b * CC + kt_ * 64 + srow)) * DD + head * HDIM + scol];
        vr = *(const int4*)&vt[((size_t)((b * HH + head) * HDIM + srow)) * CC + kt_ * 64 + scol];
    };
    auto WRITEK = [&](int buf) {
        *(int4*)&Ks[buf][srow * 64 + (scol ^ ((srow & 7) << 3))] = kr;
        *(int4*)&VT[buf][srow * 64 + (scol ^ ((srow & 7) << 3))] = vr;
    };
    auto TILE = [&](int kt, int buf) {
        const ushort* Kb = Ks[buf];
        const ushort* Vb = VT[buf];
        f32x4 sac[4] = {};
        __builtin_amdgcn_s_setprio(1);
#pragma unroll
        for (int ks = 0; ks < 2; ++ks) {
            int dcol = ks * 32 + lhi * 8;
            int arow = wq0 + l15;
            bf16x8 af = *(const bf16x8*)&Qs[arow * 64 + (dcol ^ ((arow & 7) << 3))];
#pragma unroll
            for (int n = 0; n < 4; ++n) {
                int krow = n * 16 + l15;
                bf16x8 bfr = *(const bf16x8*)&Kb[krow * 64 + (dcol ^ ((krow & 7) << 3))];
                sac[n] = __builtin_amdgcn_mfma_f32_16x16x32_bf16(af, bfr, sac[n], 0, 0, 0);
            }
        }
        __builtin_amdgcn_s_setprio(0);

        if (kt >= 2 * qt) {               // diagonal-region tiles (last two)
            const int kb0 = kt * 64;
#pragma unroll
            for (int r = 0; r < 4; ++r) {
                int qrow_g = qbase + wq0 + lhi * 4 + r;
                float p0 = __expf(sac[0][r] - mstat);
                float p1 = __expf(sac[1][r] - mstat);
                float p2 = __expf(sac[2][r] - mstat);
                float p3 = __expf(sac[3][r] - mstat);
                if (kb0 + l15      > qrow_g) p0 = 0.f;
                if (kb0 + 16 + l15 > qrow_g) p1 = 0.f;
                if (kb0 + 32 + l15 > qrow_g) p2 = 0.f;
                if (kb0 + 48 + l15 > qrow_g) p3 = 0.f;
                lpart[r] += (p0 + p1) + (p2 + p3);
                int qrow_l = wq0 + lhi * 4 + r;
                int pb = qrow_l * 64, sw = (qrow_l & 7) << 3;
                Ps[pb + ((l15)      ^ sw)] = (ushort)f2bf(p0);
                Ps[pb + ((16 + l15) ^ sw)] = (ushort)f2bf(p1);
                Ps[pb + ((32 + l15) ^ sw)] = (ushort)f2bf(p2);
                Ps[pb + ((48 + l15) ^ sw)] = (ushort)f2bf(p3);
            }
        } else {
#pragma unroll
            for (int r = 0; r < 4; ++r) {
                float p0 = __expf(sac[0][r] - mstat);
                float p1 = __expf(sac[1][r] - mstat);
                float p2 = __expf(sac[2][r] - mstat);
                float p3 = __expf(sac[3][r] - mstat);
                lpart[r] += (p0 + p1) + (p2 + p3);
                int qrow_l = wq0 + lhi * 4 + r;
                int pb = qrow_l * 64, sw = (qrow_l & 7) << 3;
                Ps[pb + ((l15)      ^ sw)] = (ushort)f2bf(p0);
                Ps[pb + ((16 + l15) ^ sw)] = (ushort)f2bf(p1);
                Ps[pb + ((32 + l15) ^ sw)] = (ushort)f2bf(p2);
                Ps[pb + ((48 + l15) ^ sw)] = (ushort)f2bf(p3);
            }
        }

        __builtin_amdgcn_s_setprio(1);
#pragma unroll
        for (int ks = 0; ks < 2; ++ks) {
            int kcol = ks * 32 + lhi * 8;
            int arow = wq0 + l15;
            bf16x8 pf = *(const bf16x8*)&Ps[arow * 64 + (kcol ^ ((arow & 7) << 3))];
#pragma unroll
            for (int n = 0; n < 4; ++n) {
                int vrow = n * 16 + l15;
                bf16x8 vf = *(const bf16x8*)&Vb[vrow * 64 + (kcol ^ ((vrow & 7) << 3))];
                oacc[n] = __builtin_amdgcn_mfma_f32_16x16x32_bf16(pf, vf, oacc[n], 0, 0, 0);
            }
        }
        __builtin_amdgcn_s_setprio(0);
    };

    // Double-buffered pipeline: ONE barrier per tile.
    LOADK(0);
    WRITEK(0);
    for (int kt = 0; kt < NT; ++kt) {
        if (kt + 1 < NT) LOADK(kt + 1);   // global loads fly under TILE(kt)
        __syncthreads();                  // buf[kt&1] writes visible to all waves
        TILE(kt, kt & 1);
        if (kt + 1 < NT) WRITEK((kt + 1) & 1);
    }

    // single deferred row-sum reduce (16 lanes per row), then divide + store
#pragma unroll
    for (int r = 0; r < 4; ++r) {
        float ls = lpart[r];
#pragma unroll
        for (int off = 1; off < 16; off <<= 1) ls += __shfl_xor(ls, off);
        float inv = 1.0f / ls;
        int qrow_g = qbase + wq0 + lhi * 4 + r;
        size_t base = ((size_t)(b * CC + qrow_g)) * DD + head * HDIM;
#pragma unroll
        for (int n = 0; n < 4; ++n)
            y[base + n * 16 + l15] = (ushort)f2bf(oacc[n][r] * inv);
    }
}

// ---------------- final: out = (h + scale*(a0+a1)) * valid  (h, partials bf16) ------------
__global__ void residmask_kernel(const ushort* __restrict__ h, const ushort* __restrict__ a0,
                                 const ushort* __restrict__ a1,
                                 const float* __restrict__ scale,
                                 const int* __restrict__ nch,
                                 float* __restrict__ out) {
    int idx = blockIdx.x * blockDim.x + threadIdx.x;   // per float4
    size_t off = (size_t)idx * 4;
    int c = (idx >> 8) & (CC - 1);
    int b = idx >> 18;
    uint2 hu = *(const uint2*)&h[off];
    uint2 pa = *(const uint2*)&a0[off];
    uint2 pb = *(const uint2*)&a1[off];
    float4 sv = *(const float4*)&scale[(idx & 255) * 4];
    float4 hv;
    hv.x = bf2f(hu.x & 0xffff) + sv.x * (bf2f(pa.x & 0xffff) + bf2f(pb.x & 0xffff));
    hv.y = bf2f(hu.x >> 16)    + sv.y * (bf2f(pa.x >> 16)    + bf2f(pb.x >> 16));
    hv.z = bf2f(hu.y & 0xffff) + sv.z * (bf2f(pa.y & 0xffff) + bf2f(pb.y & 0xffff));
    hv.w = bf2f(hu.y >> 16)    + sv.w * (bf2f(pa.y >> 16)    + bf2f(pb.y >> 16));
    if (c >= nch[b]) hv = make_float4(0.f, 0.f, 0.f, 0.f);
    *(float4*)&out[off] = hv;
}

extern "C" void kernel_launch(void* const* d_in, const int* in_sizes, int n_in,
                              void* d_out, int out_size, void* d_ws, size_t ws_size,
                              hipStream_t stream) {
    const float* x        = (const float*)d_in[0];
    const int*   boundary = (const int*)d_in[1];
    const float* Wq       = (const float*)d_in[2];
    const float* Wk       = (const float*)d_in[3];
    const float* Wv       = (const float*)d_in[4];
    const float* Wo       = (const float*)d_in[5];
    const float* qg       = (const float*)d_in[6];
    const float* fcw      = (const float*)d_in[7];
    const float* projw    = (const float*)d_in[8];
    const float* ascale   = (const float*)d_in[9];
    const float* mscale   = (const float*)d_in[10];
    const float* rmix     = (const float*)d_in[11];
    float* out = (float*)d_out;

    const size_t NTOK = (size_t)BB * CC * DD;           // 4M elems
    const size_t NHID = (size_t)BB * CC * DFF;          // 16M elems
    const size_t D2   = (size_t)DD * DD;                // 1M elems

    ushort* hb   = (ushort*)d_ws;                       // 4M bf16 residual h
    ushort* x0b  = hb + NTOK;                           // 4M bf16
    ushort* pb0  = x0b + NTOK;                          // 4M bf16 split-K partial 0
    ushort* pb1  = pb0 + NTOK;                          // 4M bf16 split-K partial 1
    ushort* xnb  = pb1 + NTOK;                          // 4M bf16
    ushort* ybf  = xnb + NTOK;                          // 4M bf16
    ushort* hidb = ybf + NTOK;                          // 16M bf16 (q/k during attn)
    ushort* wbuf = hidb + NHID;                         // 16M bf16 weights (12M used)
    ushort* vtb  = wbuf + NHID;                         // 4M bf16 (V transposed, direct)
    float*  cosT = (float*)(vtb + NTOK);
    float*  sinT = cosT + (size_t)CC * 32;
    int*    starts = (int*)(sinT + (size_t)CC * 32);
    int*    nch    = starts + BB * (CC + 1);

    ushort* qbb = hidb;                  // bf16 q (normed+RoPE'd by fused epilogue)
    ushort* kbb = hidb + NTOK;           // bf16 k

    ushort* wqkv = wbuf;                 // [0, 3M)
    ushort* wwo  = wbuf + 3 * D2;        // [3M, 4M)
    ushort* wfc  = wbuf + 4 * D2;        // [4M, 8M)
    ushort* wpj  = wbuf + 8 * D2;        // [8M, 12M)

    const int M = BB * CC;  // 4096 rows
    const int CASTL = (int)(12 * D2 / 8 / 256);         // 6144 blocks

    rope_init_kernel<<<CC * 32 / 256, 256, 0, stream>>>(cosT, sinT);
    scan_kernel<<<BB, 1024, 0, stream>>>(boundary, starts, nch);
    latents_kernel<<<dim3(CC, BB), 256, 0, stream>>>(x, starts, hb, x0b);
    rmsmix_kernel<<<M, 256, 0, stream>>>(hb, x0b, rmix, hb, xnb);   // layer-0 entry

    for (int l = 0; l < LL; ++l) {
        // one mega-cast for all this layer's weights
        castlayer_kernel<<<CASTL, 256, 0, stream>>>(Wq + l * D2, Wk + l * D2, Wv + l * D2,
                                                    Wo + l * D2,
                                                    fcw + (size_t)l * DFF * DD,
                                                    projw + (size_t)l * DD * DFF, wbuf);
        // fused QKV + qknorm epilogue; v written directly transposed into vtb
        gemm_bf16<3><<<dim3(3 * DD / 128, M / 128, 1), 512, 0, stream>>>(
            xnb, wqkv, qbb, kbb, vtb, cosT, sinT, qg + l * HH, M, 3 * DD, DD, DD, DD, 0);
        // MFMA attention -> ybf (QBLK=128, KVBLK=64, dbuf, balanced qt remap)
        attn_mfma<<<dim3(8, HH, BB), 512, 0, stream>>>(qbb, kbb, vtb, ybf, qg + l * HH);
        // a = y @ Wo^T, split-K=2 -> bf16 partials pb0,pb1; fused resid+rms -> xnb
        gemm_bf16<0><<<dim3(DD / 128, M / 128, 2), 512, 0, stream>>>(
            ybf, wwo, pb0, nullptr, nullptr, nullptr, nullptr, nullptr,
            M, DD, DD / 2, DD, DD, NTOK);
        residrms_kernel<0><<<M, 256, 0, stream>>>(hb, pb0, pb1, ascale + l * DD,
                                                  nullptr, nullptr, xnb);
        // MLP: fc (relu^2, bf16) then proj split-K=2 (bf16 partials)
        gemm_bf16<1><<<dim3(DFF / 128, M / 128, 1), 512, 0, stream>>>(
            xnb, wfc, hidb, nullptr, nullptr, nullptr, nullptr, nullptr,
            M, DFF, DD, DD, DD, 0);
        gemm_bf16<0><<<dim3(DD / 128, M / 128, 2), 512, 0, stream>>>(
            hidb, wpj, pb0, nullptr, nullptr, nullptr, nullptr, nullptr,
            M, DD, DFF / 2, DFF, DFF, NTOK);
        if (l < LL - 1) {
            residrms_kernel<1><<<M, 256, 0, stream>>>(hb, pb0, pb1, mscale + l * DD,
                                                      x0b, rmix + (size_t)(l + 1) * 2 * DD, xnb);
        } else {
            residmask_kernel<<<(int)(NTOK / 4 / 256), 256, 0, stream>>>(
                hb, pb0, pb1, mscale + l * DD, nch, out);
        }
    }
}